// Round 2
// baseline (3122.491 us; speedup 1.0000x reference)
//
#include <hip/hip_runtime.h>
#include <math.h>

#define B_   16
#define S_   512
#define D_   1024
#define H_   16
#define DK_  64
#define DFF_ 4096
#define NROW (B_ * S_)   // 8192
#define NEG_ (-1.0e9f)

// ---------------------------------------------------------------------------
// utility kernels
// ---------------------------------------------------------------------------
__global__ void zero_scales_k(unsigned int* p) {
    if (threadIdx.x < 3) p[threadIdx.x] = 0u;
}

__global__ void maxabs_k(const float* __restrict__ w, unsigned int* __restrict__ out, int n) {
    float m = 0.f;
    for (int i = blockIdx.x * blockDim.x + threadIdx.x; i < n; i += gridDim.x * blockDim.x)
        m = fmaxf(m, fabsf(w[i]));
#pragma unroll
    for (int off = 1; off < 64; off <<= 1)
        m = fmaxf(m, __shfl_xor(m, off));
    __shared__ float red[4];
    const int wave = threadIdx.x >> 6;
    if ((threadIdx.x & 63) == 0) red[wave] = m;
    __syncthreads();
    if (threadIdx.x == 0) {
        m = fmaxf(fmaxf(red[0], red[1]), fmaxf(red[2], red[3]));
        atomicMax(out, __float_as_uint(m));   // w>=0 bits order == float order
    }
}

__global__ void fakequant_k(const float* __restrict__ w, const unsigned int* __restrict__ smax,
                            float* __restrict__ out, int n4) {
    const float scale = __uint_as_float(*smax) * (1.0f / 127.0f);
    const int i = blockIdx.x * blockDim.x + threadIdx.x;
    if (i < n4) {
        const float4 v = ((const float4*)w)[i];
        float4 r;
        r.x = rintf(v.x / scale) * scale;
        r.y = rintf(v.y / scale) * scale;
        r.z = rintf(v.z / scale) * scale;
        r.w = rintf(v.w / scale) * scale;
        ((float4*)out)[i] = r;
    }
}

// ---------------------------------------------------------------------------
// layer norm: one block per row (D=1024, 256 threads x float4)
// ---------------------------------------------------------------------------
__global__ __launch_bounds__(256) void layernorm_k(
    const float* __restrict__ x, const float* __restrict__ g,
    const float* __restrict__ b, float* __restrict__ y)
{
    const int row = blockIdx.x;
    const int tid = threadIdx.x;
    const float* xr = x + (size_t)row * D_;
    const float4 v = *(const float4*)&xr[tid * 4];

    float s = v.x + v.y + v.z + v.w;
#pragma unroll
    for (int off = 1; off < 64; off <<= 1) s += __shfl_xor(s, off);
    __shared__ float red[8];
    const int wave = tid >> 6, lane = tid & 63;
    if (lane == 0) red[wave] = s;
    __syncthreads();
    s = red[0] + red[1] + red[2] + red[3];
    const float mu = s * (1.0f / (float)D_);

    const float d0 = v.x - mu, d1 = v.y - mu, d2 = v.z - mu, d3 = v.w - mu;
    float sq = d0 * d0 + d1 * d1 + d2 * d2 + d3 * d3;
#pragma unroll
    for (int off = 1; off < 64; off <<= 1) sq += __shfl_xor(sq, off);
    if (lane == 0) red[4 + wave] = sq;
    __syncthreads();
    sq = red[4] + red[5] + red[6] + red[7];
    const float rs = 1.0f / sqrtf(sq * (1.0f / (float)D_) + 1e-5f);

    const float4 gv = *(const float4*)&g[tid * 4];
    const float4 bv = *(const float4*)&b[tid * 4];
    float4 o;
    o.x = d0 * rs * gv.x + bv.x;
    o.y = d1 * rs * gv.y + bv.y;
    o.z = d2 * rs * gv.z + bv.z;
    o.w = d3 * rs * gv.w + bv.w;
    *(float4*)&y[(size_t)row * D_ + tid * 4] = o;
}

// ---------------------------------------------------------------------------
// fp32 tiled GEMM: C[M,N] = A[M,K] @ B[K,N] + bias (+gelu / +residual)
// 64x64 tile, BK=16, 256 threads, 4x4 per thread.
// EPI: 0 = bias, 1 = bias+gelu(exact), 2 = bias+residual
// ---------------------------------------------------------------------------
__device__ __forceinline__ float gelu_f(float v) {
    return 0.5f * v * (1.0f + erff(v * 0.70710678118654752f));
}

template <int EPI>
__global__ __launch_bounds__(256) void gemm_f32(
    const float* __restrict__ A, const float* __restrict__ Bm,
    const float* __restrict__ bias, const float* __restrict__ res,
    float* __restrict__ C, int M, int N, int K)
{
    __shared__ float As[16][68];   // [k][m], padded
    __shared__ float Bs[16][68];   // [k][n], padded

    const int tid = threadIdx.x;
    const int tx = tid & 15, ty = tid >> 4;
    const int row0 = blockIdx.y * 64, col0 = blockIdx.x * 64;

    const int ar = tid >> 2, akq = tid & 3;   // A loader: row 0..63, k-quad 0..3
    const int bk = tid >> 4, bnq = tid & 15;  // B loader: k 0..15, n-quad 0..15
    const float* Aptr = A + (size_t)(row0 + ar) * K + akq * 4;
    const float* Bptr = Bm + (size_t)bk * N + col0 + bnq * 4;

    float acc[4][4] = {};

    for (int k0 = 0; k0 < K; k0 += 16) {
        const float4 a = *(const float4*)(Aptr + k0);
        const float4 bb = *(const float4*)(Bptr + (size_t)k0 * N);
        As[akq * 4 + 0][ar] = a.x;
        As[akq * 4 + 1][ar] = a.y;
        As[akq * 4 + 2][ar] = a.z;
        As[akq * 4 + 3][ar] = a.w;
        *(float4*)&Bs[bk][bnq * 4] = bb;
        __syncthreads();
#pragma unroll
        for (int kk = 0; kk < 16; ++kk) {
            const float4 av = *(const float4*)&As[kk][ty * 4];
            const float4 bv = *(const float4*)&Bs[kk][tx * 4];
            acc[0][0] = fmaf(av.x, bv.x, acc[0][0]);
            acc[0][1] = fmaf(av.x, bv.y, acc[0][1]);
            acc[0][2] = fmaf(av.x, bv.z, acc[0][2]);
            acc[0][3] = fmaf(av.x, bv.w, acc[0][3]);
            acc[1][0] = fmaf(av.y, bv.x, acc[1][0]);
            acc[1][1] = fmaf(av.y, bv.y, acc[1][1]);
            acc[1][2] = fmaf(av.y, bv.z, acc[1][2]);
            acc[1][3] = fmaf(av.y, bv.w, acc[1][3]);
            acc[2][0] = fmaf(av.z, bv.x, acc[2][0]);
            acc[2][1] = fmaf(av.z, bv.y, acc[2][1]);
            acc[2][2] = fmaf(av.z, bv.z, acc[2][2]);
            acc[2][3] = fmaf(av.z, bv.w, acc[2][3]);
            acc[3][0] = fmaf(av.w, bv.x, acc[3][0]);
            acc[3][1] = fmaf(av.w, bv.y, acc[3][1]);
            acc[3][2] = fmaf(av.w, bv.z, acc[3][2]);
            acc[3][3] = fmaf(av.w, bv.w, acc[3][3]);
        }
        __syncthreads();
    }

    const float4 bv4 = *(const float4*)&bias[col0 + tx * 4];
#pragma unroll
    for (int i = 0; i < 4; ++i) {
        const int r = row0 + ty * 4 + i;
        float o0 = acc[i][0] + bv4.x;
        float o1 = acc[i][1] + bv4.y;
        float o2 = acc[i][2] + bv4.z;
        float o3 = acc[i][3] + bv4.w;
        if (EPI == 1) { o0 = gelu_f(o0); o1 = gelu_f(o1); o2 = gelu_f(o2); o3 = gelu_f(o3); }
        if (EPI == 2) {
            const float4 rv = *(const float4*)(res + (size_t)r * N + col0 + tx * 4);
            o0 += rv.x; o1 += rv.y; o2 += rv.z; o3 += rv.w;
        }
        float4 ov; ov.x = o0; ov.y = o1; ov.z = o2; ov.w = o3;
        *(float4*)(C + (size_t)r * N + col0 + tx * 4) = ov;
    }
}

// ---------------------------------------------------------------------------
// flash attention, fp32. grid = (S/64, B*H), 256 threads.
// q,k,v,out are (B,S,D) with head h occupying columns [h*64, h*64+64).
// scale folded into Q at load. mask (B,1,S,S) int32: 0 -> -1e9.
//
// Tile = 64 rows x 64 d = 4096 floats; 256 threads x 4 float4 each.
// Loader: row lr = tid>>2, d-quads (tid&3)+4j, j=0..3  (per-wave: 16 rows
// x 64B contiguous -> coalesced).
// ---------------------------------------------------------------------------
__global__ __launch_bounds__(256) void attn_flash_k(
    const float* __restrict__ q, const float* __restrict__ k,
    const float* __restrict__ v, const int* __restrict__ mask,
    float* __restrict__ o)
{
    const int qt = blockIdx.x;          // q tile 0..7
    const int bh = blockIdx.y;          // 0..255
    const int b = bh >> 4, h = bh & 15;

    __shared__ float Qt[64][68];   // [d][qrow]
    __shared__ float Kt[64][68];   // [d][krow]
    __shared__ float Vs[64][68];   // [krow][d]
    __shared__ float Pt[64][68];   // [kcol][qrow]

    const int tid = threadIdx.x;
    const int tx = tid & 15, ty = tid >> 4;
    const int lr = tid >> 2, ldq0 = tid & 3;   // loader: row 0..63, base d-quad

    {
        const float sc = 0.125f;   // 1/sqrt(64)
        const float* qrow = &q[((size_t)(b * S_ + qt * 64 + lr)) * D_ + h * 64];
#pragma unroll
        for (int j = 0; j < 4; ++j) {
            const int dq = ldq0 + 4 * j;           // 0..15
            const float4 a = *(const float4*)&qrow[dq * 4];
            Qt[dq * 4 + 0][lr] = a.x * sc;
            Qt[dq * 4 + 1][lr] = a.y * sc;
            Qt[dq * 4 + 2][lr] = a.z * sc;
            Qt[dq * 4 + 3][lr] = a.w * sc;
        }
    }

    float o_acc[4][4] = {};
    float m_r[4] = {-INFINITY, -INFINITY, -INFINITY, -INFINITY};
    float l_r[4] = {0.f, 0.f, 0.f, 0.f};

    for (int kt = 0; kt < 8; ++kt) {
        __syncthreads();   // guards Kt/Vs/Pt reuse from previous iteration
        {
            const size_t rowoff = ((size_t)(b * S_ + kt * 64 + lr)) * D_ + h * 64;
#pragma unroll
            for (int j = 0; j < 4; ++j) {
                const int dq = ldq0 + 4 * j;       // 0..15
                const float4 kk4 = *(const float4*)&k[rowoff + dq * 4];
                Kt[dq * 4 + 0][lr] = kk4.x;
                Kt[dq * 4 + 1][lr] = kk4.y;
                Kt[dq * 4 + 2][lr] = kk4.z;
                Kt[dq * 4 + 3][lr] = kk4.w;
                const float4 vv4 = *(const float4*)&v[rowoff + dq * 4];
                *(float4*)&Vs[lr][dq * 4] = vv4;
            }
        }
        __syncthreads();

        // S = Q*K^T over d
        float sacc[4][4] = {};
#pragma unroll
        for (int d = 0; d < 64; ++d) {
            const float4 qv = *(const float4*)&Qt[d][ty * 4];
            const float4 kv = *(const float4*)&Kt[d][tx * 4];
            sacc[0][0] = fmaf(qv.x, kv.x, sacc[0][0]);
            sacc[0][1] = fmaf(qv.x, kv.y, sacc[0][1]);
            sacc[0][2] = fmaf(qv.x, kv.z, sacc[0][2]);
            sacc[0][3] = fmaf(qv.x, kv.w, sacc[0][3]);
            sacc[1][0] = fmaf(qv.y, kv.x, sacc[1][0]);
            sacc[1][1] = fmaf(qv.y, kv.y, sacc[1][1]);
            sacc[1][2] = fmaf(qv.y, kv.z, sacc[1][2]);
            sacc[1][3] = fmaf(qv.y, kv.w, sacc[1][3]);
            sacc[2][0] = fmaf(qv.z, kv.x, sacc[2][0]);
            sacc[2][1] = fmaf(qv.z, kv.y, sacc[2][1]);
            sacc[2][2] = fmaf(qv.z, kv.z, sacc[2][2]);
            sacc[2][3] = fmaf(qv.z, kv.w, sacc[2][3]);
            sacc[3][0] = fmaf(qv.w, kv.x, sacc[3][0]);
            sacc[3][1] = fmaf(qv.w, kv.y, sacc[3][1]);
            sacc[3][2] = fmaf(qv.w, kv.z, sacc[3][2]);
            sacc[3][3] = fmaf(qv.w, kv.w, sacc[3][3]);
        }

        // mask + online softmax (per row i; 16 lanes sharing ty own one row group)
        float p[4][4];
#pragma unroll
        for (int i = 0; i < 4; ++i) {
            const int qg = qt * 64 + ty * 4 + i;
            const int4 mk = *(const int4*)&mask[((size_t)(b * S_ + qg)) * S_ + kt * 64 + tx * 4];
            const float s0 = mk.x ? sacc[i][0] : NEG_;
            const float s1 = mk.y ? sacc[i][1] : NEG_;
            const float s2 = mk.z ? sacc[i][2] : NEG_;
            const float s3 = mk.w ? sacc[i][3] : NEG_;
            float pm = fmaxf(fmaxf(s0, s1), fmaxf(s2, s3));
            pm = fmaxf(pm, __shfl_xor(pm, 1));
            pm = fmaxf(pm, __shfl_xor(pm, 2));
            pm = fmaxf(pm, __shfl_xor(pm, 4));
            pm = fmaxf(pm, __shfl_xor(pm, 8));
            const float mnew = fmaxf(m_r[i], pm);
            const float alpha = expf(m_r[i] - mnew);   // exp(-inf)=0 on first tile
            const float p0 = expf(s0 - mnew);
            const float p1 = expf(s1 - mnew);
            const float p2 = expf(s2 - mnew);
            const float p3 = expf(s3 - mnew);
            float rsum = p0 + p1 + p2 + p3;
            rsum += __shfl_xor(rsum, 1);
            rsum += __shfl_xor(rsum, 2);
            rsum += __shfl_xor(rsum, 4);
            rsum += __shfl_xor(rsum, 8);
            l_r[i] = l_r[i] * alpha + rsum;
            m_r[i] = mnew;
            o_acc[i][0] *= alpha;
            o_acc[i][1] *= alpha;
            o_acc[i][2] *= alpha;
            o_acc[i][3] *= alpha;
            p[i][0] = p0; p[i][1] = p1; p[i][2] = p2; p[i][3] = p3;
        }

        // stage P transposed: Pt[kcol][qrow]
#pragma unroll
        for (int i = 0; i < 4; ++i) {
            Pt[tx * 4 + 0][ty * 4 + i] = p[i][0];
            Pt[tx * 4 + 1][ty * 4 + i] = p[i][1];
            Pt[tx * 4 + 2][ty * 4 + i] = p[i][2];
            Pt[tx * 4 + 3][ty * 4 + i] = p[i][3];
        }
        __syncthreads();

        // O += P * V
#pragma unroll
        for (int j = 0; j < 64; ++j) {
            const float4 pv = *(const float4*)&Pt[j][ty * 4];
            const float4 vv = *(const float4*)&Vs[j][tx * 4];
            o_acc[0][0] = fmaf(pv.x, vv.x, o_acc[0][0]);
            o_acc[0][1] = fmaf(pv.x, vv.y, o_acc[0][1]);
            o_acc[0][2] = fmaf(pv.x, vv.z, o_acc[0][2]);
            o_acc[0][3] = fmaf(pv.x, vv.w, o_acc[0][3]);
            o_acc[1][0] = fmaf(pv.y, vv.x, o_acc[1][0]);
            o_acc[1][1] = fmaf(pv.y, vv.y, o_acc[1][1]);
            o_acc[1][2] = fmaf(pv.y, vv.z, o_acc[1][2]);
            o_acc[1][3] = fmaf(pv.y, vv.w, o_acc[1][3]);
            o_acc[2][0] = fmaf(pv.z, vv.x, o_acc[2][0]);
            o_acc[2][1] = fmaf(pv.z, vv.y, o_acc[2][1]);
            o_acc[2][2] = fmaf(pv.z, vv.z, o_acc[2][2]);
            o_acc[2][3] = fmaf(pv.z, vv.w, o_acc[2][3]);
            o_acc[3][0] = fmaf(pv.w, vv.x, o_acc[3][0]);
            o_acc[3][1] = fmaf(pv.w, vv.y, o_acc[3][1]);
            o_acc[3][2] = fmaf(pv.w, vv.z, o_acc[3][2]);
            o_acc[3][3] = fmaf(pv.w, vv.w, o_acc[3][3]);
        }
    }

#pragma unroll
    for (int i = 0; i < 4; ++i) {
        const float inv = 1.0f / l_r[i];
        const int qg = qt * 64 + ty * 4 + i;
        float4 ov;
        ov.x = o_acc[i][0] * inv;
        ov.y = o_acc[i][1] * inv;
        ov.z = o_acc[i][2] * inv;
        ov.w = o_acc[i][3] * inv;
        *(float4*)&o[((size_t)(b * S_ + qg)) * D_ + h * 64 + tx * 4] = ov;
    }
}

// ---------------------------------------------------------------------------
// launch
// ---------------------------------------------------------------------------
extern "C" void kernel_launch(void* const* d_in, const int* in_sizes, int n_in,
                              void* d_out, int out_size, void* d_ws, size_t ws_size,
                              hipStream_t stream)
{
    const float* x    = (const float*)d_in[0];
    const int*   mask = (const int*)d_in[1];
    const float* wq   = (const float*)d_in[2];
    const float* bq   = (const float*)d_in[3];
    const float* wk   = (const float*)d_in[4];
    const float* bk   = (const float*)d_in[5];
    const float* wv   = (const float*)d_in[6];
    const float* bv   = (const float*)d_in[7];
    const float* wo   = (const float*)d_in[8];
    const float* bo   = (const float*)d_in[9];
    const float* w1   = (const float*)d_in[10];
    const float* b1   = (const float*)d_in[11];
    const float* w2   = (const float*)d_in[12];
    const float* b2   = (const float*)d_in[13];
    const float* ln1g = (const float*)d_in[14];
    const float* ln1b = (const float*)d_in[15];
    const float* ln2g = (const float*)d_in[16];
    const float* ln2b = (const float*)d_in[17];
    float* out = (float*)d_out;
    char* ws = (char*)d_ws;

    const size_t MB = 1024 * 1024;
    // layout (peak ~160MB + 12B):
    //   h/h2 : 0   - 32MB
    //   q    : 32  - 64MB      \
    //   k    : 64  - 96MB       |  reused as ff1 (32-160MB) after o-proj
    //   v    : 96  - 128MB      |
    //   attn : 128 - 160MB     /
    //   fq(wq,wk,wv): 128-140MB (dead before attn is written)
    //   scales: 160MB, 3 uints
    float* h    = (float*)(ws);
    float* qb   = (float*)(ws + 32 * MB);
    float* kb   = (float*)(ws + 64 * MB);
    float* vb   = (float*)(ws + 96 * MB);
    float* attn = (float*)(ws + 128 * MB);
    float* ff1  = (float*)(ws + 32 * MB);
    float* fqq  = (float*)(ws + 128 * MB);
    float* fqk  = (float*)(ws + 132 * MB);
    float* fqv  = (float*)(ws + 136 * MB);
    unsigned int* scales = (unsigned int*)(ws + 160 * MB);

    const int NW = D_ * D_;   // 1048576 weight elements

    zero_scales_k<<<1, 64, 0, stream>>>(scales);
    maxabs_k<<<256, 256, 0, stream>>>(wq, scales + 0, NW);
    maxabs_k<<<256, 256, 0, stream>>>(wk, scales + 1, NW);
    maxabs_k<<<256, 256, 0, stream>>>(wv, scales + 2, NW);
    fakequant_k<<<NW / 4 / 256, 256, 0, stream>>>(wq, scales + 0, fqq, NW / 4);
    fakequant_k<<<NW / 4 / 256, 256, 0, stream>>>(wk, scales + 1, fqk, NW / 4);
    fakequant_k<<<NW / 4 / 256, 256, 0, stream>>>(wv, scales + 2, fqv, NW / 4);

    layernorm_k<<<NROW, 256, 0, stream>>>(x, ln1g, ln1b, h);

    dim3 gD(D_ / 64, NROW / 64);      // (16, 128)
    gemm_f32<0><<<gD, 256, 0, stream>>>(h, fqq, bq, nullptr, qb, NROW, D_, D_);
    gemm_f32<0><<<gD, 256, 0, stream>>>(h, fqk, bk, nullptr, kb, NROW, D_, D_);
    gemm_f32<0><<<gD, 256, 0, stream>>>(h, fqv, bv, nullptr, vb, NROW, D_, D_);

    attn_flash_k<<<dim3(S_ / 64, B_ * H_), 256, 0, stream>>>(qb, kb, vb, mask, attn);

    // x2 = x + attn @ wo + bo   -> d_out
    gemm_f32<2><<<gD, 256, 0, stream>>>(attn, wo, bo, x, out, NROW, D_, D_);

    // h2 = LN2(x2) (reuse h)
    layernorm_k<<<NROW, 256, 0, stream>>>(out, ln2g, ln2b, h);

    // ff1 = gelu(h2 @ w1 + b1)
    gemm_f32<1><<<dim3(DFF_ / 64, NROW / 64), 256, 0, stream>>>(h, w1, b1, nullptr, ff1, NROW, DFF_, D_);

    // out = x2 + ff1 @ w2 + b2  (res==C==out: each thread reads-then-writes its own elems)
    gemm_f32<2><<<gD, 256, 0, stream>>>(ff1, w2, b2, out, out, NROW, D_, DFF_);
}

// Round 3
// 864.251 us; speedup vs baseline: 3.6129x; 3.6129x over previous
//
#include <hip/hip_runtime.h>
#include <hip/hip_bf16.h>
#include <math.h>

#define B_   16
#define S_   512
#define D_   1024
#define H_   16
#define DK_  64
#define DFF_ 4096
#define NROW (B_ * S_)   // 8192
#define NEG_ (-1.0e9f)

typedef __attribute__((ext_vector_type(8))) short short8v;   // 8 bf16 = 4 VGPRs
typedef __attribute__((ext_vector_type(4))) float f32x4;

// async global->LDS, 16B per lane. LDS dest = wave-uniform base + lane*16.
__device__ __forceinline__ void load_lds16(const void* g, void* l) {
    __builtin_amdgcn_global_load_lds(
        reinterpret_cast<const __attribute__((address_space(1))) unsigned int*>(
            reinterpret_cast<uintptr_t>(g)),
        reinterpret_cast<__attribute__((address_space(3))) unsigned int*>(
            reinterpret_cast<uintptr_t>(l)),
        16, 0, 0);
}

__device__ __forceinline__ ushort f2bf_raw(float f) {
    __hip_bfloat16 h = __float2bfloat16(f);
    return *(ushort*)&h;
}

// ---------------------------------------------------------------------------
// utility kernels
// ---------------------------------------------------------------------------
__global__ void zero_scales_k(unsigned int* p) {
    if (threadIdx.x < 3) p[threadIdx.x] = 0u;
}

__global__ void maxabs_k(const float* __restrict__ w, unsigned int* __restrict__ out, int n) {
    float m = 0.f;
    for (int i = blockIdx.x * blockDim.x + threadIdx.x; i < n; i += gridDim.x * blockDim.x)
        m = fmaxf(m, fabsf(w[i]));
#pragma unroll
    for (int off = 1; off < 64; off <<= 1)
        m = fmaxf(m, __shfl_xor(m, off));
    __shared__ float red[4];
    const int wave = threadIdx.x >> 6;
    if ((threadIdx.x & 63) == 0) red[wave] = m;
    __syncthreads();
    if (threadIdx.x == 0) {
        m = fmaxf(fmaxf(red[0], red[1]), fmaxf(red[2], red[3]));
        atomicMax(out, __float_as_uint(m));   // w>=0: uint bit order == float order
    }
}

// transpose fp32 W[K][N] -> bf16 Wt[N][K], optional int8 fake-quant (smax!=null)
// grid (N/32, K/32), block (32,8)
__global__ __launch_bounds__(256) void transq_k(
    const float* __restrict__ W, const unsigned int* __restrict__ smax,
    __hip_bfloat16* __restrict__ Wt, int K, int N)
{
    __shared__ float t[32][33];
    const int n0 = blockIdx.x * 32, k0 = blockIdx.y * 32;
    const int tx = threadIdx.x, ty = threadIdx.y;
    float scale = 1.0f;
    if (smax) scale = __uint_as_float(*smax) * (1.0f / 127.0f);
#pragma unroll
    for (int i = 0; i < 4; ++i) {
        float v = W[(size_t)(k0 + ty + 8 * i) * N + n0 + tx];
        if (smax) v = rintf(v / scale) * scale;
        t[ty + 8 * i][tx] = v;
    }
    __syncthreads();
#pragma unroll
    for (int i = 0; i < 4; ++i)
        Wt[(size_t)(n0 + ty + 8 * i) * K + k0 + tx] = __float2bfloat16(t[tx][ty + 8 * i]);
}

// ---------------------------------------------------------------------------
// layer norm: fp32 in -> bf16 out. one block per row, 256 threads x float4
// ---------------------------------------------------------------------------
__global__ __launch_bounds__(256) void ln_bf16_k(
    const float* __restrict__ x, const float* __restrict__ g,
    const float* __restrict__ b, __hip_bfloat16* __restrict__ y)
{
    const int row = blockIdx.x;
    const int tid = threadIdx.x;
    const float4 v = *(const float4*)&x[(size_t)row * D_ + tid * 4];

    float s = v.x + v.y + v.z + v.w;
#pragma unroll
    for (int off = 1; off < 64; off <<= 1) s += __shfl_xor(s, off);
    __shared__ float red[8];
    const int wave = tid >> 6, lane = tid & 63;
    if (lane == 0) red[wave] = s;
    __syncthreads();
    s = red[0] + red[1] + red[2] + red[3];
    const float mu = s * (1.0f / (float)D_);

    const float d0 = v.x - mu, d1 = v.y - mu, d2 = v.z - mu, d3 = v.w - mu;
    float sq = d0 * d0 + d1 * d1 + d2 * d2 + d3 * d3;
#pragma unroll
    for (int off = 1; off < 64; off <<= 1) sq += __shfl_xor(sq, off);
    if (lane == 0) red[4 + wave] = sq;
    __syncthreads();
    sq = red[4] + red[5] + red[6] + red[7];
    const float rs = 1.0f / sqrtf(sq * (1.0f / (float)D_) + 1e-5f);

    const float4 gv = *(const float4*)&g[tid * 4];
    const float4 bv = *(const float4*)&b[tid * 4];
    union { ushort4 u4; ushort u[4]; } cv;
    cv.u[0] = f2bf_raw(d0 * rs * gv.x + bv.x);
    cv.u[1] = f2bf_raw(d1 * rs * gv.y + bv.y);
    cv.u[2] = f2bf_raw(d2 * rs * gv.z + bv.z);
    cv.u[3] = f2bf_raw(d3 * rs * gv.w + bv.w);
    *(ushort4*)&y[(size_t)row * D_ + tid * 4] = cv.u4;
}

// ---------------------------------------------------------------------------
// bf16 MFMA GEMM (m97 structure): C[M,N] = A[M,K] @ Bt[N,K]^T + bias
// 128x128 tile, BK=32, 256 threads (4 waves, 2x2), 4x4 16x16x32 frags/wave.
// EPI: 0 = bias, 1 = bias+gelu(exact), 2 = bias+residual(fp32)
// OBF: true -> write bf16, else fp32
// ---------------------------------------------------------------------------
__device__ __forceinline__ float gelu_f(float v) {
    return 0.5f * v * (1.0f + erff(v * 0.70710678118654752f));
}

template <int EPI, bool OBF>
__global__ __launch_bounds__(256) void gemm_bf16(
    const __hip_bfloat16* __restrict__ A, const __hip_bfloat16* __restrict__ Bt,
    const float* __restrict__ bias, const float* __restrict__ res,
    void* __restrict__ C, int M, int N, int K)
{
    __shared__ __align__(16) __hip_bfloat16 Asm[128 * 32];
    __shared__ __align__(16) __hip_bfloat16 Bsm[128 * 32];

    const int tid = threadIdx.x;
    const int w = tid >> 6, l = tid & 63;
    const int lhi = l >> 4, llo = l & 15;
    const int row0 = blockIdx.y * 128, col0 = blockIdx.x * 128;
    const int wr = w >> 1, wc = w & 1;

    f32x4 acc[4][4] = {};

    // staging: chunk c in [0,512): row=c>>2, 16B k-seg=c&3. thread t does c=t, c=t+256.
    const int r0 = tid >> 2, ks0 = tid & 3;
    const __hip_bfloat16* Ag0 = A + (size_t)(row0 + r0) * K + ks0 * 8;
    const __hip_bfloat16* Ag1 = A + (size_t)(row0 + r0 + 64) * K + ks0 * 8;
    const __hip_bfloat16* Bg0 = Bt + (size_t)(col0 + r0) * K + ks0 * 8;
    const __hip_bfloat16* Bg1 = Bt + (size_t)(col0 + r0 + 64) * K + ks0 * 8;
    char* const AsmB = (char*)Asm;
    char* const BsmB = (char*)Bsm;
    void* const lA0 = AsmB + w * 1024;            // wave-uniform dest bases
    void* const lA1 = AsmB + 4096 + w * 1024;
    void* const lB0 = BsmB + w * 1024;
    void* const lB1 = BsmB + 4096 + w * 1024;

    const __hip_bfloat16* const Afrag = &Asm[(wr * 64 + llo) * 32 + lhi * 8];
    const __hip_bfloat16* const Bfrag = &Bsm[(wc * 64 + llo) * 32 + lhi * 8];

    for (int k0 = 0; k0 < K; k0 += 32) {
        load_lds16(Ag0 + k0, lA0);
        load_lds16(Ag1 + k0, lA1);
        load_lds16(Bg0 + k0, lB0);
        load_lds16(Bg1 + k0, lB1);
        __syncthreads();   // drains vmcnt (compiler inserts) -> LDS staged

        short8v a[4], b[4];
#pragma unroll
        for (int m = 0; m < 4; ++m) a[m] = *(const short8v*)(Afrag + m * 16 * 32);
#pragma unroll
        for (int n = 0; n < 4; ++n) b[n] = *(const short8v*)(Bfrag + n * 16 * 32);
#pragma unroll
        for (int m = 0; m < 4; ++m)
#pragma unroll
            for (int n = 0; n < 4; ++n)
                acc[m][n] = __builtin_amdgcn_mfma_f32_16x16x32_bf16(a[m], b[n], acc[m][n], 0, 0, 0);
        __syncthreads();   // all reads done before next stage overwrites
    }

    // epilogue. C/D layout: col = lane&15, row = (lane>>4)*4 + reg  [m89-verified]
#pragma unroll
    for (int n = 0; n < 4; ++n) {
        const int col = col0 + wc * 64 + n * 16 + llo;
        const float bs = bias[col];
#pragma unroll
        for (int m = 0; m < 4; ++m) {
            const int rbase = row0 + wr * 64 + m * 16 + lhi * 4;
#pragma unroll
            for (int j = 0; j < 4; ++j) {
                float v = acc[m][n][j] + bs;
                if (EPI == 1) v = gelu_f(v);
                if (EPI == 2) v += res[(size_t)(rbase + j) * N + col];
                if (OBF) ((__hip_bfloat16*)C)[(size_t)(rbase + j) * N + col] = __float2bfloat16(v);
                else     ((float*)C)[(size_t)(rbase + j) * N + col] = v;
            }
        }
    }
}

// ---------------------------------------------------------------------------
// flash attention, fp32 math, bf16 out. grid = (S/64, B*H), 256 threads.
// ---------------------------------------------------------------------------
__global__ __launch_bounds__(256) void attn_flash_k(
    const float* __restrict__ q, const float* __restrict__ k,
    const float* __restrict__ v, const int* __restrict__ mask,
    __hip_bfloat16* __restrict__ o)
{
    const int qt = blockIdx.x;
    const int bh = blockIdx.y;
    const int b = bh >> 4, h = bh & 15;

    __shared__ float Qt[64][68];
    __shared__ float Kt[64][68];
    __shared__ float Vs[64][68];
    __shared__ float Pt[64][68];

    const int tid = threadIdx.x;
    const int tx = tid & 15, ty = tid >> 4;
    const int lr = tid >> 2, ldq0 = tid & 3;

    {
        const float sc = 0.125f;
        const float* qrow = &q[((size_t)(b * S_ + qt * 64 + lr)) * D_ + h * 64];
#pragma unroll
        for (int j = 0; j < 4; ++j) {
            const int dq = ldq0 + 4 * j;
            const float4 a = *(const float4*)&qrow[dq * 4];
            Qt[dq * 4 + 0][lr] = a.x * sc;
            Qt[dq * 4 + 1][lr] = a.y * sc;
            Qt[dq * 4 + 2][lr] = a.z * sc;
            Qt[dq * 4 + 3][lr] = a.w * sc;
        }
    }

    float o_acc[4][4] = {};
    float m_r[4] = {-INFINITY, -INFINITY, -INFINITY, -INFINITY};
    float l_r[4] = {0.f, 0.f, 0.f, 0.f};

    for (int kt = 0; kt < 8; ++kt) {
        __syncthreads();
        {
            const size_t rowoff = ((size_t)(b * S_ + kt * 64 + lr)) * D_ + h * 64;
#pragma unroll
            for (int j = 0; j < 4; ++j) {
                const int dq = ldq0 + 4 * j;
                const float4 kk4 = *(const float4*)&k[rowoff + dq * 4];
                Kt[dq * 4 + 0][lr] = kk4.x;
                Kt[dq * 4 + 1][lr] = kk4.y;
                Kt[dq * 4 + 2][lr] = kk4.z;
                Kt[dq * 4 + 3][lr] = kk4.w;
                const float4 vv4 = *(const float4*)&v[rowoff + dq * 4];
                *(float4*)&Vs[lr][dq * 4] = vv4;
            }
        }
        __syncthreads();

        float sacc[4][4] = {};
#pragma unroll
        for (int d = 0; d < 64; ++d) {
            const float4 qv = *(const float4*)&Qt[d][ty * 4];
            const float4 kv = *(const float4*)&Kt[d][tx * 4];
            sacc[0][0] = fmaf(qv.x, kv.x, sacc[0][0]);
            sacc[0][1] = fmaf(qv.x, kv.y, sacc[0][1]);
            sacc[0][2] = fmaf(qv.x, kv.z, sacc[0][2]);
            sacc[0][3] = fmaf(qv.x, kv.w, sacc[0][3]);
            sacc[1][0] = fmaf(qv.y, kv.x, sacc[1][0]);
            sacc[1][1] = fmaf(qv.y, kv.y, sacc[1][1]);
            sacc[1][2] = fmaf(qv.y, kv.z, sacc[1][2]);
            sacc[1][3] = fmaf(qv.y, kv.w, sacc[1][3]);
            sacc[2][0] = fmaf(qv.z, kv.x, sacc[2][0]);
            sacc[2][1] = fmaf(qv.z, kv.y, sacc[2][1]);
            sacc[2][2] = fmaf(qv.z, kv.z, sacc[2][2]);
            sacc[2][3] = fmaf(qv.z, kv.w, sacc[2][3]);
            sacc[3][0] = fmaf(qv.w, kv.x, sacc[3][0]);
            sacc[3][1] = fmaf(qv.w, kv.y, sacc[3][1]);
            sacc[3][2] = fmaf(qv.w, kv.z, sacc[3][2]);
            sacc[3][3] = fmaf(qv.w, kv.w, sacc[3][3]);
        }

        float p[4][4];
#pragma unroll
        for (int i = 0; i < 4; ++i) {
            const int qg = qt * 64 + ty * 4 + i;
            const int4 mk = *(const int4*)&mask[((size_t)(b * S_ + qg)) * S_ + kt * 64 + tx * 4];
            const float s0 = mk.x ? sacc[i][0] : NEG_;
            const float s1 = mk.y ? sacc[i][1] : NEG_;
            const float s2 = mk.z ? sacc[i][2] : NEG_;
            const float s3 = mk.w ? sacc[i][3] : NEG_;
            float pm = fmaxf(fmaxf(s0, s1), fmaxf(s2, s3));
            pm = fmaxf(pm, __shfl_xor(pm, 1));
            pm = fmaxf(pm, __shfl_xor(pm, 2));
            pm = fmaxf(pm, __shfl_xor(pm, 4));
            pm = fmaxf(pm, __shfl_xor(pm, 8));
            const float mnew = fmaxf(m_r[i], pm);
            const float alpha = expf(m_r[i] - mnew);
            const float p0 = expf(s0 - mnew);
            const float p1 = expf(s1 - mnew);
            const float p2 = expf(s2 - mnew);
            const float p3 = expf(s3 - mnew);
            float rsum = p0 + p1 + p2 + p3;
            rsum += __shfl_xor(rsum, 1);
            rsum += __shfl_xor(rsum, 2);
            rsum += __shfl_xor(rsum, 4);
            rsum += __shfl_xor(rsum, 8);
            l_r[i] = l_r[i] * alpha + rsum;
            m_r[i] = mnew;
            o_acc[i][0] *= alpha;
            o_acc[i][1] *= alpha;
            o_acc[i][2] *= alpha;
            o_acc[i][3] *= alpha;
            p[i][0] = p0; p[i][1] = p1; p[i][2] = p2; p[i][3] = p3;
        }

#pragma unroll
        for (int i = 0; i < 4; ++i) {
            Pt[tx * 4 + 0][ty * 4 + i] = p[i][0];
            Pt[tx * 4 + 1][ty * 4 + i] = p[i][1];
            Pt[tx * 4 + 2][ty * 4 + i] = p[i][2];
            Pt[tx * 4 + 3][ty * 4 + i] = p[i][3];
        }
        __syncthreads();

#pragma unroll
        for (int j = 0; j < 64; ++j) {
            const float4 pv = *(const float4*)&Pt[j][ty * 4];
            const float4 vv = *(const float4*)&Vs[j][tx * 4];
            o_acc[0][0] = fmaf(pv.x, vv.x, o_acc[0][0]);
            o_acc[0][1] = fmaf(pv.x, vv.y, o_acc[0][1]);
            o_acc[0][2] = fmaf(pv.x, vv.z, o_acc[0][2]);
            o_acc[0][3] = fmaf(pv.x, vv.w, o_acc[0][3]);
            o_acc[1][0] = fmaf(pv.y, vv.x, o_acc[1][0]);
            o_acc[1][1] = fmaf(pv.y, vv.y, o_acc[1][1]);
            o_acc[1][2] = fmaf(pv.y, vv.z, o_acc[1][2]);
            o_acc[1][3] = fmaf(pv.y, vv.w, o_acc[1][3]);
            o_acc[2][0] = fmaf(pv.z, vv.x, o_acc[2][0]);
            o_acc[2][1] = fmaf(pv.z, vv.y, o_acc[2][1]);
            o_acc[2][2] = fmaf(pv.z, vv.z, o_acc[2][2]);
            o_acc[2][3] = fmaf(pv.z, vv.w, o_acc[2][3]);
            o_acc[3][0] = fmaf(pv.w, vv.x, o_acc[3][0]);
            o_acc[3][1] = fmaf(pv.w, vv.y, o_acc[3][1]);
            o_acc[3][2] = fmaf(pv.w, vv.z, o_acc[3][2]);
            o_acc[3][3] = fmaf(pv.w, vv.w, o_acc[3][3]);
        }
    }

#pragma unroll
    for (int i = 0; i < 4; ++i) {
        const float inv = 1.0f / l_r[i];
        const int qg = qt * 64 + ty * 4 + i;
        union { ushort4 u4; ushort u[4]; } cv;
        cv.u[0] = f2bf_raw(o_acc[i][0] * inv);
        cv.u[1] = f2bf_raw(o_acc[i][1] * inv);
        cv.u[2] = f2bf_raw(o_acc[i][2] * inv);
        cv.u[3] = f2bf_raw(o_acc[i][3] * inv);
        *(ushort4*)&o[((size_t)(b * S_ + qg)) * D_ + h * 64 + tx * 4] = cv.u4;
    }
}

// ---------------------------------------------------------------------------
// launch
// ---------------------------------------------------------------------------
extern "C" void kernel_launch(void* const* d_in, const int* in_sizes, int n_in,
                              void* d_out, int out_size, void* d_ws, size_t ws_size,
                              hipStream_t stream)
{
    const float* x    = (const float*)d_in[0];
    const int*   mask = (const int*)d_in[1];
    const float* wq   = (const float*)d_in[2];
    const float* bq   = (const float*)d_in[3];
    const float* wk   = (const float*)d_in[4];
    const float* bk   = (const float*)d_in[5];
    const float* wv   = (const float*)d_in[6];
    const float* bv   = (const float*)d_in[7];
    const float* wo   = (const float*)d_in[8];
    const float* bo   = (const float*)d_in[9];
    const float* w1   = (const float*)d_in[10];
    const float* b1   = (const float*)d_in[11];
    const float* w2   = (const float*)d_in[12];
    const float* b2   = (const float*)d_in[13];
    const float* ln1g = (const float*)d_in[14];
    const float* ln1b = (const float*)d_in[15];
    const float* ln2g = (const float*)d_in[16];
    const float* ln2b = (const float*)d_in[17];
    float* out = (float*)d_out;
    char* ws = (char*)d_ws;

    const size_t MB = 1024 * 1024;
    // ws layout (peak 152MB + 12B):
    //   hb/h2b (bf16)  : 0   - 16
    //   q,k,v (fp32)   : 16-48, 48-80, 80-112
    //   ff1b (bf16)    : 16 - 80   (reuses q/k after attn)
    //   attnb (bf16)   : 112 - 128
    //   fqq/fqk/fqv/wo t (bf16 [N][K]) : 128-130-132-134-136
    //   w1t, w2t (bf16): 136-144, 144-152
    //   scales         : 152, 3 uints
    __hip_bfloat16* hb    = (__hip_bfloat16*)(ws);
    float*          qb    = (float*)(ws + 16 * MB);
    float*          kb    = (float*)(ws + 48 * MB);
    float*          vb    = (float*)(ws + 80 * MB);
    __hip_bfloat16* ff1b  = (__hip_bfloat16*)(ws + 16 * MB);
    __hip_bfloat16* attnb = (__hip_bfloat16*)(ws + 112 * MB);
    __hip_bfloat16* fqqt  = (__hip_bfloat16*)(ws + 128 * MB);
    __hip_bfloat16* fqkt  = (__hip_bfloat16*)(ws + 130 * MB);
    __hip_bfloat16* fqvt  = (__hip_bfloat16*)(ws + 132 * MB);
    __hip_bfloat16* wot   = (__hip_bfloat16*)(ws + 134 * MB);
    __hip_bfloat16* w1t   = (__hip_bfloat16*)(ws + 136 * MB);
    __hip_bfloat16* w2t   = (__hip_bfloat16*)(ws + 144 * MB);
    unsigned int*   scales = (unsigned int*)(ws + 152 * MB);

    const int NW = D_ * D_;

    zero_scales_k<<<1, 64, 0, stream>>>(scales);
    maxabs_k<<<256, 256, 0, stream>>>(wq, scales + 0, NW);
    maxabs_k<<<256, 256, 0, stream>>>(wk, scales + 1, NW);
    maxabs_k<<<256, 256, 0, stream>>>(wv, scales + 2, NW);

    const dim3 tb(32, 8);
    transq_k<<<dim3(D_ / 32, D_ / 32), tb, 0, stream>>>(wq, scales + 0, fqqt, D_, D_);
    transq_k<<<dim3(D_ / 32, D_ / 32), tb, 0, stream>>>(wk, scales + 1, fqkt, D_, D_);
    transq_k<<<dim3(D_ / 32, D_ / 32), tb, 0, stream>>>(wv, scales + 2, fqvt, D_, D_);
    transq_k<<<dim3(D_ / 32, D_ / 32), tb, 0, stream>>>(wo, nullptr, wot, D_, D_);
    transq_k<<<dim3(DFF_ / 32, D_ / 32), tb, 0, stream>>>(w1, nullptr, w1t, D_, DFF_);
    transq_k<<<dim3(D_ / 32, DFF_ / 32), tb, 0, stream>>>(w2, nullptr, w2t, DFF_, D_);

    ln_bf16_k<<<NROW, 256, 0, stream>>>(x, ln1g, ln1b, hb);

    const dim3 gD(D_ / 128, NROW / 128);      // (8, 64)
    gemm_bf16<0, false><<<gD, 256, 0, stream>>>(hb, fqqt, bq, nullptr, qb, NROW, D_, D_);
    gemm_bf16<0, false><<<gD, 256, 0, stream>>>(hb, fqkt, bk, nullptr, kb, NROW, D_, D_);
    gemm_bf16<0, false><<<gD, 256, 0, stream>>>(hb, fqvt, bv, nullptr, vb, NROW, D_, D_);

    attn_flash_k<<<dim3(S_ / 64, B_ * H_), 256, 0, stream>>>(qb, kb, vb, mask, attnb);

    // x2 = x + attn @ wo + bo -> out (fp32)
    gemm_bf16<2, false><<<gD, 256, 0, stream>>>(attnb, wot, bo, x, out, NROW, D_, D_);

    // h2 = LN2(x2) -> hb (bf16)
    ln_bf16_k<<<NROW, 256, 0, stream>>>(out, ln2g, ln2b, hb);

    // ff1 = gelu(h2 @ w1 + b1) -> bf16
    gemm_bf16<1, true><<<dim3(DFF_ / 128, NROW / 128), 256, 0, stream>>>(hb, w1t, b1, nullptr, ff1b, NROW, DFF_, D_);

    // out = x2 + ff1 @ w2 + b2  (res == C == out: lanes touch only their own elems)
    gemm_bf16<2, false><<<gD, 256, 0, stream>>>(ff1b, w2t, b2, out, out, NROW, D_, DFF_);
}

// Round 4
// 533.306 us; speedup vs baseline: 5.8550x; 1.6206x over previous
//
#include <hip/hip_runtime.h>
#include <hip/hip_bf16.h>
#include <math.h>

#define B_   16
#define S_   512
#define D_   1024
#define H_   16
#define DK_  64
#define DFF_ 4096
#define NROW (B_ * S_)   // 8192
#define NEG_ (-1.0e9f)

typedef __attribute__((ext_vector_type(8))) short short8v;   // 8 bf16 = 4 VGPRs
typedef __attribute__((ext_vector_type(4))) float f32x4;

// async global->LDS, 16B per lane. LDS dest = wave-uniform base + lane*16.
__device__ __forceinline__ void load_lds16(const void* g, void* l) {
    __builtin_amdgcn_global_load_lds(
        reinterpret_cast<const __attribute__((address_space(1))) unsigned int*>(
            reinterpret_cast<uintptr_t>(g)),
        reinterpret_cast<__attribute__((address_space(3))) unsigned int*>(
            reinterpret_cast<uintptr_t>(l)),
        16, 0, 0);
}

__device__ __forceinline__ ushort f2bf_raw(float f) {
    __hip_bfloat16 h = __float2bfloat16(f);
    return *(ushort*)&h;
}

// ---------------------------------------------------------------------------
// utility kernels
// ---------------------------------------------------------------------------
__global__ void zero_scales_k(unsigned int* p) {
    if (threadIdx.x < 3) p[threadIdx.x] = 0u;
}

__global__ void maxabs_k(const float* __restrict__ w, unsigned int* __restrict__ out, int n) {
    float m = 0.f;
    for (int i = blockIdx.x * blockDim.x + threadIdx.x; i < n; i += gridDim.x * blockDim.x)
        m = fmaxf(m, fabsf(w[i]));
#pragma unroll
    for (int off = 1; off < 64; off <<= 1)
        m = fmaxf(m, __shfl_xor(m, off));
    __shared__ float red[4];
    const int wave = threadIdx.x >> 6;
    if ((threadIdx.x & 63) == 0) red[wave] = m;
    __syncthreads();
    if (threadIdx.x == 0) {
        m = fmaxf(fmaxf(red[0], red[1]), fmaxf(red[2], red[3]));
        atomicMax(out, __float_as_uint(m));   // w>=0: uint bit order == float order
    }
}

// transpose fp32 W[K][N] -> bf16 Wt[N][K], optional int8 fake-quant (smax!=null)
// grid (N/32, K/32), block (32,8)
__global__ __launch_bounds__(256) void transq_k(
    const float* __restrict__ W, const unsigned int* __restrict__ smax,
    __hip_bfloat16* __restrict__ Wt, int K, int N)
{
    __shared__ float t[32][33];
    const int n0 = blockIdx.x * 32, k0 = blockIdx.y * 32;
    const int tx = threadIdx.x, ty = threadIdx.y;
    float scale = 1.0f;
    if (smax) scale = __uint_as_float(*smax) * (1.0f / 127.0f);
#pragma unroll
    for (int i = 0; i < 4; ++i) {
        float v = W[(size_t)(k0 + ty + 8 * i) * N + n0 + tx];
        if (smax) v = rintf(v / scale) * scale;
        t[ty + 8 * i][tx] = v;
    }
    __syncthreads();
#pragma unroll
    for (int i = 0; i < 4; ++i)
        Wt[(size_t)(n0 + ty + 8 * i) * K + k0 + tx] = __float2bfloat16(t[tx][ty + 8 * i]);
}

// ---------------------------------------------------------------------------
// layer norm: fp32 in -> bf16 out. one block per row, 256 threads x float4
// ---------------------------------------------------------------------------
__global__ __launch_bounds__(256) void ln_bf16_k(
    const float* __restrict__ x, const float* __restrict__ g,
    const float* __restrict__ b, __hip_bfloat16* __restrict__ y)
{
    const int row = blockIdx.x;
    const int tid = threadIdx.x;
    const float4 v = *(const float4*)&x[(size_t)row * D_ + tid * 4];

    float s = v.x + v.y + v.z + v.w;
#pragma unroll
    for (int off = 1; off < 64; off <<= 1) s += __shfl_xor(s, off);
    __shared__ float red[8];
    const int wave = tid >> 6, lane = tid & 63;
    if (lane == 0) red[wave] = s;
    __syncthreads();
    s = red[0] + red[1] + red[2] + red[3];
    const float mu = s * (1.0f / (float)D_);

    const float d0 = v.x - mu, d1 = v.y - mu, d2 = v.z - mu, d3 = v.w - mu;
    float sq = d0 * d0 + d1 * d1 + d2 * d2 + d3 * d3;
#pragma unroll
    for (int off = 1; off < 64; off <<= 1) sq += __shfl_xor(sq, off);
    if (lane == 0) red[4 + wave] = sq;
    __syncthreads();
    sq = red[4] + red[5] + red[6] + red[7];
    const float rs = 1.0f / sqrtf(sq * (1.0f / (float)D_) + 1e-5f);

    const float4 gv = *(const float4*)&g[tid * 4];
    const float4 bv = *(const float4*)&b[tid * 4];
    union { ushort4 u4; ushort u[4]; } cv;
    cv.u[0] = f2bf_raw(d0 * rs * gv.x + bv.x);
    cv.u[1] = f2bf_raw(d1 * rs * gv.y + bv.y);
    cv.u[2] = f2bf_raw(d2 * rs * gv.z + bv.z);
    cv.u[3] = f2bf_raw(d3 * rs * gv.w + bv.w);
    *(ushort4*)&y[(size_t)row * D_ + tid * 4] = cv.u4;
}

// ---------------------------------------------------------------------------
// bf16 MFMA GEMM (m97 structure): C[M,N] = A[M,K] @ Bt[N,K]^T + bias
// 128x128 tile, BK=32, 256 threads (4 waves, 2x2), 4x4 16x16x32 frags/wave.
// EPI: 0 = bias            (OBF selects fp32/bf16 out)
//      1 = bias+gelu       (OBF)
//      2 = bias+residual   (fp32 res; OBF)
//      3 = bias, bf16 out TRANSPOSED per-head: vt[b][h][dk][s]   (V proj)
//      4 = (bias)*0.125, bf16 out                                 (Q proj)
// ---------------------------------------------------------------------------
__device__ __forceinline__ float gelu_f(float v) {
    return 0.5f * v * (1.0f + erff(v * 0.70710678118654752f));
}

template <int EPI, bool OBF>
__global__ __launch_bounds__(256) void gemm_bf16(
    const __hip_bfloat16* __restrict__ A, const __hip_bfloat16* __restrict__ Bt,
    const float* __restrict__ bias, const float* __restrict__ res,
    void* __restrict__ C, int M, int N, int K)
{
    __shared__ __align__(16) __hip_bfloat16 Asm[128 * 32];
    __shared__ __align__(16) __hip_bfloat16 Bsm[128 * 32];

    const int tid = threadIdx.x;
    const int w = tid >> 6, l = tid & 63;
    const int lhi = l >> 4, llo = l & 15;
    const int row0 = blockIdx.y * 128, col0 = blockIdx.x * 128;
    const int wr = w >> 1, wc = w & 1;

    f32x4 acc[4][4] = {};

    const int r0 = tid >> 2, ks0 = tid & 3;
    const __hip_bfloat16* Ag0 = A + (size_t)(row0 + r0) * K + ks0 * 8;
    const __hip_bfloat16* Ag1 = A + (size_t)(row0 + r0 + 64) * K + ks0 * 8;
    const __hip_bfloat16* Bg0 = Bt + (size_t)(col0 + r0) * K + ks0 * 8;
    const __hip_bfloat16* Bg1 = Bt + (size_t)(col0 + r0 + 64) * K + ks0 * 8;
    char* const AsmB = (char*)Asm;
    char* const BsmB = (char*)Bsm;
    void* const lA0 = AsmB + w * 1024;
    void* const lA1 = AsmB + 4096 + w * 1024;
    void* const lB0 = BsmB + w * 1024;
    void* const lB1 = BsmB + 4096 + w * 1024;

    const __hip_bfloat16* const Afrag = &Asm[(wr * 64 + llo) * 32 + lhi * 8];
    const __hip_bfloat16* const Bfrag = &Bsm[(wc * 64 + llo) * 32 + lhi * 8];

    for (int k0 = 0; k0 < K; k0 += 32) {
        load_lds16(Ag0 + k0, lA0);
        load_lds16(Ag1 + k0, lA1);
        load_lds16(Bg0 + k0, lB0);
        load_lds16(Bg1 + k0, lB1);
        __syncthreads();

        short8v a[4], b[4];
#pragma unroll
        for (int m = 0; m < 4; ++m) a[m] = *(const short8v*)(Afrag + m * 16 * 32);
#pragma unroll
        for (int n = 0; n < 4; ++n) b[n] = *(const short8v*)(Bfrag + n * 16 * 32);
#pragma unroll
        for (int m = 0; m < 4; ++m)
#pragma unroll
            for (int n = 0; n < 4; ++n)
                acc[m][n] = __builtin_amdgcn_mfma_f32_16x16x32_bf16(a[m], b[n], acc[m][n], 0, 0, 0);
        __syncthreads();
    }

    // epilogue. C/D layout: col = lane&15, row = (lane>>4)*4 + reg  [verified]
#pragma unroll
    for (int n = 0; n < 4; ++n) {
        const int col = col0 + wc * 64 + n * 16 + llo;
        const float bs = bias[col];
#pragma unroll
        for (int m = 0; m < 4; ++m) {
            const int rbase = row0 + wr * 64 + m * 16 + lhi * 4;
            if (EPI == 3) {
                // vt[b][h][dk][s], s = rbase&511 .. +3 (consecutive, 4-aligned)
                const int bb = rbase >> 9, s = rbase & 511;
                const int hh = col >> 6, dk = col & 63;
                union { ushort4 u4; ushort u[4]; } pk;
#pragma unroll
                for (int j = 0; j < 4; ++j) pk.u[j] = f2bf_raw(acc[m][n][j] + bs);
                *(ushort4*)&((ushort*)C)[(((size_t)(bb * 16 + hh) * 64 + dk) << 9) + s] = pk.u4;
            } else {
#pragma unroll
                for (int j = 0; j < 4; ++j) {
                    float v = acc[m][n][j] + bs;
                    if (EPI == 1) v = gelu_f(v);
                    if (EPI == 2) v += res[(size_t)(rbase + j) * N + col];
                    if (EPI == 4) v *= 0.125f;
                    if (OBF) ((__hip_bfloat16*)C)[(size_t)(rbase + j) * N + col] = __float2bfloat16(v);
                    else     ((float*)C)[(size_t)(rbase + j) * N + col] = v;
                }
            }
        }
    }
}

// ---------------------------------------------------------------------------
// MFMA flash attention. grid = (S/64, B*H), 256 threads (4 waves).
// q,k: bf16 [B,S,D] (head slice cols h*64..); q pre-scaled by 1/8.
// vt: bf16 [B][H][DK][S].  mask int32 [B,1,S,S].  o: bf16 [B,S,D].
// Wave w owns q-rows [w*16, w*16+16). Per k-tile (64 tokens):
//   QK^T: 2 ksteps x 4 colfrags MFMA; online softmax fp32; P->bf16 via LDS
//   (wave-private rows, no barrier); PV: 2 ksteps x 4 dfrags MFMA.
// LDS rows padded to 72 elems (144B): bank stride 4 -> worst 2-way (free).
// ---------------------------------------------------------------------------
__global__ __launch_bounds__(256) void attn_mfma_k(
    const __hip_bfloat16* __restrict__ q, const __hip_bfloat16* __restrict__ k,
    const __hip_bfloat16* __restrict__ vt, const int* __restrict__ mask,
    __hip_bfloat16* __restrict__ o)
{
    const int qt = blockIdx.x;
    const int bh = blockIdx.y;
    const int b = bh >> 4, h = bh & 15;

    __shared__ __align__(16) __hip_bfloat16 Qs[64 * 72];
    __shared__ __align__(16) __hip_bfloat16 Ks[64 * 72];
    __shared__ __align__(16) __hip_bfloat16 Vts[64 * 72];
    __shared__ __align__(16) __hip_bfloat16 Pt[64 * 72];

    const int tid = threadIdx.x;
    const int w = tid >> 6, l = tid & 63;
    const int llo = l & 15, lhi = l >> 4;
    const int srow = tid >> 2, schk = tid & 3;   // staging: row, 16-elem chunk

    // stage Q tile [64 q][64 d] (first in-loop barrier covers it)
    {
        const __hip_bfloat16* qg =
            q + (size_t)(b * S_ + qt * 64 + srow) * D_ + h * 64 + schk * 16;
        *(short8v*)&Qs[srow * 72 + schk * 16] = *(const short8v*)qg;
        *(short8v*)&Qs[srow * 72 + schk * 16 + 8] = *(const short8v*)(qg + 8);
    }

    f32x4 oacc[4] = {};                       // [dfrag]; reg j = q row lhi*4+j
    float m_r[4] = {-INFINITY, -INFINITY, -INFINITY, -INFINITY};
    float l_r[4] = {0.f, 0.f, 0.f, 0.f};

    for (int kt = 0; kt < 8; ++kt) {
        // stage K tile [64 tok][64 d] and Vt tile [64 d][64 tok]
        {
            const __hip_bfloat16* kg =
                k + (size_t)(b * S_ + kt * 64 + srow) * D_ + h * 64 + schk * 16;
            const short8v k0v = *(const short8v*)kg;
            const short8v k1v = *(const short8v*)(kg + 8);
            const __hip_bfloat16* vg =
                vt + (((size_t)(b * 16 + h) * 64 + srow) << 9) + kt * 64 + schk * 16;
            const short8v v0v = *(const short8v*)vg;
            const short8v v1v = *(const short8v*)(vg + 8);
            __syncthreads();   // prior iter's reads of Ks/Vts done
            *(short8v*)&Ks[srow * 72 + schk * 16] = k0v;
            *(short8v*)&Ks[srow * 72 + schk * 16 + 8] = k1v;
            *(short8v*)&Vts[srow * 72 + schk * 16] = v0v;
            *(short8v*)&Vts[srow * 72 + schk * 16 + 8] = v1v;
        }
        __syncthreads();

        // S = Q K^T : rows = wave's 16 q, cols = 64 tokens
        f32x4 sacc[4] = {};
#pragma unroll
        for (int ks = 0; ks < 2; ++ks) {
            const short8v a = *(const short8v*)&Qs[(w * 16 + llo) * 72 + ks * 32 + lhi * 8];
#pragma unroll
            for (int n = 0; n < 4; ++n) {
                const short8v bf = *(const short8v*)&Ks[(n * 16 + llo) * 72 + ks * 32 + lhi * 8];
                sacc[n] = __builtin_amdgcn_mfma_f32_16x16x32_bf16(a, bf, sacc[n], 0, 0, 0);
            }
        }

        // online softmax; lane holds S[q=lhi*4+j][tok=n*16+llo]
#pragma unroll
        for (int j = 0; j < 4; ++j) {
            const int qg_ = qt * 64 + w * 16 + lhi * 4 + j;
            const int* mrow = mask + (size_t)(b * S_ + qg_) * S_ + kt * 64;
            float s0 = mrow[llo]      ? sacc[0][j] : NEG_;
            float s1 = mrow[llo + 16] ? sacc[1][j] : NEG_;
            float s2 = mrow[llo + 32] ? sacc[2][j] : NEG_;
            float s3 = mrow[llo + 48] ? sacc[3][j] : NEG_;
            float pm = fmaxf(fmaxf(s0, s1), fmaxf(s2, s3));
            pm = fmaxf(pm, __shfl_xor(pm, 1));
            pm = fmaxf(pm, __shfl_xor(pm, 2));
            pm = fmaxf(pm, __shfl_xor(pm, 4));
            pm = fmaxf(pm, __shfl_xor(pm, 8));
            const float mnew = fmaxf(m_r[j], pm);
            const float alpha = expf(m_r[j] - mnew);
            const float p0 = expf(s0 - mnew);
            const float p1 = expf(s1 - mnew);
            const float p2 = expf(s2 - mnew);
            const float p3 = expf(s3 - mnew);
            float rsum = p0 + p1 + p2 + p3;
            rsum += __shfl_xor(rsum, 1);
            rsum += __shfl_xor(rsum, 2);
            rsum += __shfl_xor(rsum, 4);
            rsum += __shfl_xor(rsum, 8);
            l_r[j] = l_r[j] * alpha + rsum;
            m_r[j] = mnew;
#pragma unroll
            for (int df = 0; df < 4; ++df) oacc[df][j] *= alpha;
            // stage P row (wave-private rows; lgkmcnt orders write->read)
            const int prow = (w * 16 + lhi * 4 + j) * 72;
            Pt[prow + llo]      = __float2bfloat16(p0);
            Pt[prow + llo + 16] = __float2bfloat16(p1);
            Pt[prow + llo + 32] = __float2bfloat16(p2);
            Pt[prow + llo + 48] = __float2bfloat16(p3);
        }

        // O += P V : A = P[16 q x 64 tok], B = Vt[d][tok]
#pragma unroll
        for (int ks = 0; ks < 2; ++ks) {
            const short8v pa = *(const short8v*)&Pt[(w * 16 + llo) * 72 + ks * 32 + lhi * 8];
#pragma unroll
            for (int df = 0; df < 4; ++df) {
                const short8v vb = *(const short8v*)&Vts[(df * 16 + llo) * 72 + ks * 32 + lhi * 8];
                oacc[df] = __builtin_amdgcn_mfma_f32_16x16x32_bf16(pa, vb, oacc[df], 0, 0, 0);
            }
        }
    }

    // write O: row q = w*16+lhi*4+j, col d = df*16+llo
#pragma unroll
    for (int j = 0; j < 4; ++j) {
        const float inv = 1.0f / l_r[j];
        __hip_bfloat16* orow =
            o + (size_t)(b * S_ + qt * 64 + w * 16 + lhi * 4 + j) * D_ + h * 64;
#pragma unroll
        for (int df = 0; df < 4; ++df)
            orow[df * 16 + llo] = __float2bfloat16(oacc[df][j] * inv);
    }
}

// ---------------------------------------------------------------------------
// launch
// ---------------------------------------------------------------------------
extern "C" void kernel_launch(void* const* d_in, const int* in_sizes, int n_in,
                              void* d_out, int out_size, void* d_ws, size_t ws_size,
                              hipStream_t stream)
{
    const float* x    = (const float*)d_in[0];
    const int*   mask = (const int*)d_in[1];
    const float* wq   = (const float*)d_in[2];
    const float* bq   = (const float*)d_in[3];
    const float* wk   = (const float*)d_in[4];
    const float* bk   = (const float*)d_in[5];
    const float* wv   = (const float*)d_in[6];
    const float* bv   = (const float*)d_in[7];
    const float* wo   = (const float*)d_in[8];
    const float* bo   = (const float*)d_in[9];
    const float* w1   = (const float*)d_in[10];
    const float* b1   = (const float*)d_in[11];
    const float* w2   = (const float*)d_in[12];
    const float* b2   = (const float*)d_in[13];
    const float* ln1g = (const float*)d_in[14];
    const float* ln1b = (const float*)d_in[15];
    const float* ln2g = (const float*)d_in[16];
    const float* ln2b = (const float*)d_in[17];
    float* out = (float*)d_out;
    char* ws = (char*)d_ws;

    const size_t MB = 1024 * 1024;
    // ws layout (peak 104MB + 12B):
    //   hb (bf16)           : 0  - 16    (LN1 out; later LN2 out)
    //   qbh (bf16, scaled)  : 16 - 32
    //   kbh (bf16)          : 32 - 48
    //   vth (bf16 [B,H,DK,S]): 48 - 64
    //   attnb (bf16)        : 64 - 80
    //   ff1b (bf16)         : 16 - 80    (reuses q/k/vt/attn after o-proj)
    //   weights bf16 [N][K] : 80 - 104 (fqq 80, fqk 82, fqv 84, wo 86, w1 88, w2 96)
    //   scales              : 104MB, 3 uints
    __hip_bfloat16* hb    = (__hip_bfloat16*)(ws);
    __hip_bfloat16* qbh   = (__hip_bfloat16*)(ws + 16 * MB);
    __hip_bfloat16* kbh   = (__hip_bfloat16*)(ws + 32 * MB);
    __hip_bfloat16* vth   = (__hip_bfloat16*)(ws + 48 * MB);
    __hip_bfloat16* attnb = (__hip_bfloat16*)(ws + 64 * MB);
    __hip_bfloat16* ff1b  = (__hip_bfloat16*)(ws + 16 * MB);
    __hip_bfloat16* fqqt  = (__hip_bfloat16*)(ws + 80 * MB);
    __hip_bfloat16* fqkt  = (__hip_bfloat16*)(ws + 82 * MB);
    __hip_bfloat16* fqvt  = (__hip_bfloat16*)(ws + 84 * MB);
    __hip_bfloat16* wot   = (__hip_bfloat16*)(ws + 86 * MB);
    __hip_bfloat16* w1t   = (__hip_bfloat16*)(ws + 88 * MB);
    __hip_bfloat16* w2t   = (__hip_bfloat16*)(ws + 96 * MB);
    unsigned int*   scales = (unsigned int*)(ws + 104 * MB);

    const int NW = D_ * D_;

    zero_scales_k<<<1, 64, 0, stream>>>(scales);
    maxabs_k<<<256, 256, 0, stream>>>(wq, scales + 0, NW);
    maxabs_k<<<256, 256, 0, stream>>>(wk, scales + 1, NW);
    maxabs_k<<<256, 256, 0, stream>>>(wv, scales + 2, NW);

    const dim3 tb(32, 8);
    transq_k<<<dim3(D_ / 32, D_ / 32), tb, 0, stream>>>(wq, scales + 0, fqqt, D_, D_);
    transq_k<<<dim3(D_ / 32, D_ / 32), tb, 0, stream>>>(wk, scales + 1, fqkt, D_, D_);
    transq_k<<<dim3(D_ / 32, D_ / 32), tb, 0, stream>>>(wv, scales + 2, fqvt, D_, D_);
    transq_k<<<dim3(D_ / 32, D_ / 32), tb, 0, stream>>>(wo, nullptr, wot, D_, D_);
    transq_k<<<dim3(DFF_ / 32, D_ / 32), tb, 0, stream>>>(w1, nullptr, w1t, D_, DFF_);
    transq_k<<<dim3(D_ / 32, DFF_ / 32), tb, 0, stream>>>(w2, nullptr, w2t, DFF_, D_);

    ln_bf16_k<<<NROW, 256, 0, stream>>>(x, ln1g, ln1b, hb);

    const dim3 gD(D_ / 128, NROW / 128);      // (8, 64)
    gemm_bf16<4, true><<<gD, 256, 0, stream>>>(hb, fqqt, bq, nullptr, qbh, NROW, D_, D_);
    gemm_bf16<0, true><<<gD, 256, 0, stream>>>(hb, fqkt, bk, nullptr, kbh, NROW, D_, D_);
    gemm_bf16<3, true><<<gD, 256, 0, stream>>>(hb, fqvt, bv, nullptr, vth, NROW, D_, D_);

    attn_mfma_k<<<dim3(S_ / 64, B_ * H_), 256, 0, stream>>>(qbh, kbh, vth, mask, attnb);

    // x2 = x + attn @ wo + bo -> out (fp32)
    gemm_bf16<2, false><<<gD, 256, 0, stream>>>(attnb, wot, bo, x, out, NROW, D_, D_);

    // h2 = LN2(x2) -> hb (bf16)
    ln_bf16_k<<<NROW, 256, 0, stream>>>(out, ln2g, ln2b, hb);

    // ff1 = gelu(h2 @ w1 + b1) -> bf16
    gemm_bf16<1, true><<<dim3(DFF_ / 128, NROW / 128), 256, 0, stream>>>(hb, w1t, b1, nullptr, ff1b, NROW, DFF_, D_);

    // out = x2 + ff1 @ w2 + b2  (res == C == out: lanes touch only their own elems)
    gemm_bf16<2, false><<<gD, 256, 0, stream>>>(ff1b, w2t, b2, out, out, NROW, D_, DFF_);
}

// Round 5
// 499.863 us; speedup vs baseline: 6.2467x; 1.0669x over previous
//
#include <hip/hip_runtime.h>
#include <hip/hip_bf16.h>
#include <math.h>

#define B_   16
#define S_   512
#define D_   1024
#define H_   16
#define DK_  64
#define DFF_ 4096
#define NROW (B_ * S_)   // 8192
#define NEG_ (-1.0e9f)
#define SCQ_ 0.18033688011112042f   // 0.125 * log2(e): QK^T lands in log2 units

typedef __attribute__((ext_vector_type(8))) short short8v;   // 8 bf16 = 4 VGPRs
typedef __attribute__((ext_vector_type(4))) float f32x4;

__device__ __forceinline__ void load_lds16(const void* g, void* l) {
    __builtin_amdgcn_global_load_lds(
        reinterpret_cast<const __attribute__((address_space(1))) unsigned int*>(
            reinterpret_cast<uintptr_t>(g)),
        reinterpret_cast<__attribute__((address_space(3))) unsigned int*>(
            reinterpret_cast<uintptr_t>(l)),
        16, 0, 0);
}

__device__ __forceinline__ ushort f2bf_raw(float f) {
    __hip_bfloat16 h = __float2bfloat16(f);
    return *(ushort*)&h;
}

// ---------------------------------------------------------------------------
// utility kernels
// ---------------------------------------------------------------------------
__global__ void zero_scales_k(unsigned int* p) {
    if (threadIdx.x < 3) p[threadIdx.x] = 0u;
}

__global__ void maxabs_k(const float* __restrict__ w, unsigned int* __restrict__ out, int n) {
    float m = 0.f;
    for (int i = blockIdx.x * blockDim.x + threadIdx.x; i < n; i += gridDim.x * blockDim.x)
        m = fmaxf(m, fabsf(w[i]));
#pragma unroll
    for (int off = 1; off < 64; off <<= 1)
        m = fmaxf(m, __shfl_xor(m, off));
    __shared__ float red[4];
    const int wave = threadIdx.x >> 6;
    if ((threadIdx.x & 63) == 0) red[wave] = m;
    __syncthreads();
    if (threadIdx.x == 0) {
        m = fmaxf(fmaxf(red[0], red[1]), fmaxf(red[2], red[3]));
        atomicMax(out, __float_as_uint(m));
    }
}

// pack mask (B,1,S,S) int32 -> bits[B*S*(S/64)] u64; one wave per 64-token group
__global__ __launch_bounds__(256) void maskpack_k(
    const int* __restrict__ mask, unsigned long long* __restrict__ bits) {
    const int g = blockIdx.x * 4 + (threadIdx.x >> 6);
    const unsigned long long bm = __ballot(mask[(size_t)g * 64 + (threadIdx.x & 63)] != 0);
    if ((threadIdx.x & 63) == 0) bits[g] = bm;
}

// transpose fp32 W[K][N] -> bf16 Wt[N][K], optional int8 fake-quant
__global__ __launch_bounds__(256) void transq_k(
    const float* __restrict__ W, const unsigned int* __restrict__ smax,
    __hip_bfloat16* __restrict__ Wt, int K, int N)
{
    __shared__ float t[32][33];
    const int n0 = blockIdx.x * 32, k0 = blockIdx.y * 32;
    const int tx = threadIdx.x, ty = threadIdx.y;
    float scale = 1.0f;
    if (smax) scale = __uint_as_float(*smax) * (1.0f / 127.0f);
#pragma unroll
    for (int i = 0; i < 4; ++i) {
        float v = W[(size_t)(k0 + ty + 8 * i) * N + n0 + tx];
        if (smax) v = rintf(v / scale) * scale;
        t[ty + 8 * i][tx] = v;
    }
    __syncthreads();
#pragma unroll
    for (int i = 0; i < 4; ++i)
        Wt[(size_t)(n0 + ty + 8 * i) * K + k0 + tx] = __float2bfloat16(t[tx][ty + 8 * i]);
}

// ---------------------------------------------------------------------------
// layer norm fp32 -> bf16
// ---------------------------------------------------------------------------
__global__ __launch_bounds__(256) void ln_bf16_k(
    const float* __restrict__ x, const float* __restrict__ g,
    const float* __restrict__ b, __hip_bfloat16* __restrict__ y)
{
    const int row = blockIdx.x;
    const int tid = threadIdx.x;
    const float4 v = *(const float4*)&x[(size_t)row * D_ + tid * 4];

    float s = v.x + v.y + v.z + v.w;
#pragma unroll
    for (int off = 1; off < 64; off <<= 1) s += __shfl_xor(s, off);
    __shared__ float red[8];
    const int wave = tid >> 6, lane = tid & 63;
    if (lane == 0) red[wave] = s;
    __syncthreads();
    s = red[0] + red[1] + red[2] + red[3];
    const float mu = s * (1.0f / (float)D_);

    const float d0 = v.x - mu, d1 = v.y - mu, d2 = v.z - mu, d3 = v.w - mu;
    float sq = d0 * d0 + d1 * d1 + d2 * d2 + d3 * d3;
#pragma unroll
    for (int off = 1; off < 64; off <<= 1) sq += __shfl_xor(sq, off);
    if (lane == 0) red[4 + wave] = sq;
    __syncthreads();
    sq = red[4] + red[5] + red[6] + red[7];
    const float rs = 1.0f / sqrtf(sq * (1.0f / (float)D_) + 1e-5f);

    const float4 gv = *(const float4*)&g[tid * 4];
    const float4 bv = *(const float4*)&b[tid * 4];
    union { ushort4 u4; ushort u[4]; } cv;
    cv.u[0] = f2bf_raw(d0 * rs * gv.x + bv.x);
    cv.u[1] = f2bf_raw(d1 * rs * gv.y + bv.y);
    cv.u[2] = f2bf_raw(d2 * rs * gv.z + bv.z);
    cv.u[3] = f2bf_raw(d3 * rs * gv.w + bv.w);
    *(ushort4*)&y[(size_t)row * D_ + tid * 4] = cv.u4;
}

__device__ __forceinline__ float gelu_f(float v) {
    return 0.5f * v * (1.0f + erff(v * 0.70710678118654752f));
}

// ---------------------------------------------------------------------------
// bf16 MFMA GEMM, 128x128 tile, BK=64, 256 threads (4 waves 2x2), 4x4 frags.
// C = A[M,K] @ Bt[N,K]^T + bias.  EPI: 0=bias 1=bias+gelu 2=bias+residual
// ---------------------------------------------------------------------------
template <int EPI, bool OBF>
__global__ __launch_bounds__(256) void gemm_bf16(
    const __hip_bfloat16* __restrict__ A, const __hip_bfloat16* __restrict__ Bt,
    const float* __restrict__ bias, const float* __restrict__ res,
    void* __restrict__ C, int M, int N, int K)
{
    __shared__ __align__(16) __hip_bfloat16 Asm[128 * 64];
    __shared__ __align__(16) __hip_bfloat16 Bsm[128 * 64];

    const int tid = threadIdx.x;
    const int w = tid >> 6, l = tid & 63;
    const int lhi = l >> 4, llo = l & 15;
    const int row0 = blockIdx.y * 128, col0 = blockIdx.x * 128;
    const int wr = w >> 1, wc = w & 1;

    f32x4 acc[4][4] = {};

    // staging: chunk c = p*256+tid; row=c>>3, 16B kseg=c&7; LDS byte = c*16
    const __hip_bfloat16* Ap[4];
    const __hip_bfloat16* Bp[4];
#pragma unroll
    for (int p = 0; p < 4; ++p) {
        const int c = p * 256 + tid;
        const int rr = c >> 3, kseg = c & 7;
        Ap[p] = A + (size_t)(row0 + rr) * K + kseg * 8;
        Bp[p] = Bt + (size_t)(col0 + rr) * K + kseg * 8;
    }
    char* const AsmB = (char*)Asm;
    char* const BsmB = (char*)Bsm;

    for (int k0 = 0; k0 < K; k0 += 64) {
#pragma unroll
        for (int p = 0; p < 4; ++p) {
            load_lds16(Ap[p] + k0, AsmB + p * 4096 + w * 1024);
            load_lds16(Bp[p] + k0, BsmB + p * 4096 + w * 1024);
        }
        __syncthreads();
#pragma unroll
        for (int kk = 0; kk < 2; ++kk) {
            short8v a[4], b[4];
#pragma unroll
            for (int m = 0; m < 4; ++m)
                a[m] = *(const short8v*)&Asm[(wr * 64 + m * 16 + llo) * 64 + kk * 32 + lhi * 8];
#pragma unroll
            for (int n = 0; n < 4; ++n)
                b[n] = *(const short8v*)&Bsm[(wc * 64 + n * 16 + llo) * 64 + kk * 32 + lhi * 8];
#pragma unroll
            for (int m = 0; m < 4; ++m)
#pragma unroll
                for (int n = 0; n < 4; ++n)
                    acc[m][n] = __builtin_amdgcn_mfma_f32_16x16x32_bf16(a[m], b[n], acc[m][n], 0, 0, 0);
        }
        __syncthreads();
    }

    // C/D layout: col = lane&15, row = (lane>>4)*4 + reg
#pragma unroll
    for (int n = 0; n < 4; ++n) {
        const int col = col0 + wc * 64 + n * 16 + llo;
        const float bs = bias[col];
#pragma unroll
        for (int m = 0; m < 4; ++m) {
            const int rbase = row0 + wr * 64 + m * 16 + lhi * 4;
#pragma unroll
            for (int j = 0; j < 4; ++j) {
                float v = acc[m][n][j] + bs;
                if (EPI == 1) v = gelu_f(v);
                if (EPI == 2) v += res[(size_t)(rbase + j) * N + col];
                if (OBF) ((__hip_bfloat16*)C)[(size_t)(rbase + j) * N + col] = __float2bfloat16(v);
                else     ((float*)C)[(size_t)(rbase + j) * N + col] = v;
            }
        }
    }
}

// ---------------------------------------------------------------------------
// fused QKV GEMM: A[M,1024] @ Wcat[3072,1024]^T. Per-col-block epilogue:
//   proj0 -> qbh bf16 *(0.125*log2e), proj1 -> kbh bf16, proj2 -> vth transposed
// ---------------------------------------------------------------------------
__global__ __launch_bounds__(256) void gemm_qkv(
    const __hip_bfloat16* __restrict__ A, const __hip_bfloat16* __restrict__ Wcat,
    const float* __restrict__ bq, const float* __restrict__ bk, const float* __restrict__ bv,
    __hip_bfloat16* __restrict__ qbh, __hip_bfloat16* __restrict__ kbh,
    __hip_bfloat16* __restrict__ vth)
{
    const int K = D_;
    __shared__ __align__(16) __hip_bfloat16 Asm[128 * 64];
    __shared__ __align__(16) __hip_bfloat16 Bsm[128 * 64];

    const int tid = threadIdx.x;
    const int w = tid >> 6, l = tid & 63;
    const int lhi = l >> 4, llo = l & 15;
    const int row0 = blockIdx.y * 128, col0 = blockIdx.x * 128;
    const int wr = w >> 1, wc = w & 1;

    f32x4 acc[4][4] = {};

    const __hip_bfloat16* Ap[4];
    const __hip_bfloat16* Bp[4];
#pragma unroll
    for (int p = 0; p < 4; ++p) {
        const int c = p * 256 + tid;
        const int rr = c >> 3, kseg = c & 7;
        Ap[p] = A + (size_t)(row0 + rr) * K + kseg * 8;
        Bp[p] = Wcat + (size_t)(col0 + rr) * K + kseg * 8;
    }
    char* const AsmB = (char*)Asm;
    char* const BsmB = (char*)Bsm;

    for (int k0 = 0; k0 < K; k0 += 64) {
#pragma unroll
        for (int p = 0; p < 4; ++p) {
            load_lds16(Ap[p] + k0, AsmB + p * 4096 + w * 1024);
            load_lds16(Bp[p] + k0, BsmB + p * 4096 + w * 1024);
        }
        __syncthreads();
#pragma unroll
        for (int kk = 0; kk < 2; ++kk) {
            short8v a[4], b[4];
#pragma unroll
            for (int m = 0; m < 4; ++m)
                a[m] = *(const short8v*)&Asm[(wr * 64 + m * 16 + llo) * 64 + kk * 32 + lhi * 8];
#pragma unroll
            for (int n = 0; n < 4; ++n)
                b[n] = *(const short8v*)&Bsm[(wc * 64 + n * 16 + llo) * 64 + kk * 32 + lhi * 8];
#pragma unroll
            for (int m = 0; m < 4; ++m)
#pragma unroll
                for (int n = 0; n < 4; ++n)
                    acc[m][n] = __builtin_amdgcn_mfma_f32_16x16x32_bf16(a[m], b[n], acc[m][n], 0, 0, 0);
        }
        __syncthreads();
    }

#pragma unroll
    for (int n = 0; n < 4; ++n) {
        const int gcol = col0 + wc * 64 + n * 16 + llo;
        const int proj = gcol >> 10, lcol = gcol & 1023;   // wave-uniform proj
        const float bs = (proj == 0 ? bq : (proj == 1 ? bk : bv))[lcol];
#pragma unroll
        for (int m = 0; m < 4; ++m) {
            const int rbase = row0 + wr * 64 + m * 16 + lhi * 4;
            if (proj == 2) {
                // vth[b][h][dk][s]; s = rbase&511..+3 consecutive
                const int bb = rbase >> 9, s = rbase & 511;
                const int hh = lcol >> 6, dk = lcol & 63;
                union { ushort4 u4; ushort u[4]; } pk;
#pragma unroll
                for (int j = 0; j < 4; ++j) pk.u[j] = f2bf_raw(acc[m][n][j] + bs);
                *(ushort4*)&((ushort*)vth)[(((size_t)(bb * 16 + hh) * 64 + dk) << 9) + s] = pk.u4;
            } else {
                __hip_bfloat16* dst = proj == 0 ? qbh : kbh;
                const float sc = proj == 0 ? SCQ_ : 1.0f;
#pragma unroll
                for (int j = 0; j < 4; ++j)
                    dst[(size_t)(rbase + j) * D_ + lcol] = __float2bfloat16((acc[m][n][j] + bs) * sc);
            }
        }
    }
}

// ---------------------------------------------------------------------------
// MFMA flash attention. grid (S/64, B*H), 256 threads (4 waves x 16 q-rows).
// q pre-scaled by 0.125*log2e -> softmax in exp2 domain (single v_exp_f32).
// mask as packed bitmasks. K/V register-prefetched one tile ahead.
// ---------------------------------------------------------------------------
__global__ __launch_bounds__(256) void attn_mfma_k(
    const __hip_bfloat16* __restrict__ q, const __hip_bfloat16* __restrict__ k,
    const __hip_bfloat16* __restrict__ vt, const unsigned long long* __restrict__ mbits,
    __hip_bfloat16* __restrict__ o)
{
    const int qt = blockIdx.x;
    const int bh = blockIdx.y;
    const int b = bh >> 4, h = bh & 15;

    __shared__ __align__(16) __hip_bfloat16 Qs[64 * 72];
    __shared__ __align__(16) __hip_bfloat16 Ks[64 * 72];
    __shared__ __align__(16) __hip_bfloat16 Vts[64 * 72];
    __shared__ __align__(16) __hip_bfloat16 Pt[64 * 72];

    const int tid = threadIdx.x;
    const int w = tid >> 6, l = tid & 63;
    const int llo = l & 15, lhi = l >> 4;
    const int srow = tid >> 2, schk = tid & 3;

    // stage Q tile [64 q][64 d]
    {
        const __hip_bfloat16* qg =
            q + (size_t)(b * S_ + qt * 64 + srow) * D_ + h * 64 + schk * 16;
        *(short8v*)&Qs[srow * 72 + schk * 16] = *(const short8v*)qg;
        *(short8v*)&Qs[srow * 72 + schk * 16 + 8] = *(const short8v*)(qg + 8);
    }

    // prefetch K/V tile 0 into regs
    const __hip_bfloat16* kptr = k + (size_t)(b * S_ + srow) * D_ + h * 64 + schk * 16;
    const __hip_bfloat16* vptr = vt + (((size_t)(b * 16 + h) * 64 + srow) << 9) + schk * 16;
    short8v kr0 = *(const short8v*)kptr;
    short8v kr1 = *(const short8v*)(kptr + 8);
    short8v vr0 = *(const short8v*)vptr;
    short8v vr1 = *(const short8v*)(vptr + 8);

    __syncthreads();   // Q staged

    // Q fragments: constant per wave, hoisted
    const short8v qa0 = *(const short8v*)&Qs[(w * 16 + llo) * 72 + lhi * 8];
    const short8v qa1 = *(const short8v*)&Qs[(w * 16 + llo) * 72 + 32 + lhi * 8];

    // mask bits base for this lane's 4 q-rows
    const unsigned long long* mrow =
        mbits + (((size_t)(b * S_ + qt * 64 + w * 16 + lhi * 4)) << 3);

    f32x4 oacc[4] = {};
    float m_r[4] = {-INFINITY, -INFINITY, -INFINITY, -INFINITY};
    float l_r[4] = {0.f, 0.f, 0.f, 0.f};

    for (int kt = 0; kt < 8; ++kt) {
        // write staged regs -> LDS (prior tile reads done via loop-end barrier)
        *(short8v*)&Ks[srow * 72 + schk * 16] = kr0;
        *(short8v*)&Ks[srow * 72 + schk * 16 + 8] = kr1;
        *(short8v*)&Vts[srow * 72 + schk * 16] = vr0;
        *(short8v*)&Vts[srow * 72 + schk * 16 + 8] = vr1;
        __syncthreads();

        // prefetch next tile (overlaps with compute below)
        short8v nk0, nk1, nv0, nv1;
        if (kt < 7) {
            const __hip_bfloat16* kp = kptr + (size_t)(kt + 1) * (64 * D_);
            const __hip_bfloat16* vp = vptr + (kt + 1) * 64;
            nk0 = *(const short8v*)kp;
            nk1 = *(const short8v*)(kp + 8);
            nv0 = *(const short8v*)vp;
            nv1 = *(const short8v*)(vp + 8);
        }

        // S = Q K^T (log2 units)
        f32x4 sacc[4] = {};
#pragma unroll
        for (int n = 0; n < 4; ++n)
            sacc[n] = __builtin_amdgcn_mfma_f32_16x16x32_bf16(
                qa0, *(const short8v*)&Ks[(n * 16 + llo) * 72 + lhi * 8], sacc[n], 0, 0, 0);
#pragma unroll
        for (int n = 0; n < 4; ++n)
            sacc[n] = __builtin_amdgcn_mfma_f32_16x16x32_bf16(
                qa1, *(const short8v*)&Ks[(n * 16 + llo) * 72 + 32 + lhi * 8], sacc[n], 0, 0, 0);

        // online softmax, exp2 domain
#pragma unroll
        for (int j = 0; j < 4; ++j) {
            const unsigned long long mb = mrow[j * 8 + kt];
            const float s0 = ((mb >> llo) & 1ull)        ? sacc[0][j] : NEG_;
            const float s1 = ((mb >> (llo + 16)) & 1ull) ? sacc[1][j] : NEG_;
            const float s2 = ((mb >> (llo + 32)) & 1ull) ? sacc[2][j] : NEG_;
            const float s3 = ((mb >> (llo + 48)) & 1ull) ? sacc[3][j] : NEG_;
            float pm = fmaxf(fmaxf(s0, s1), fmaxf(s2, s3));
            pm = fmaxf(pm, __shfl_xor(pm, 1));
            pm = fmaxf(pm, __shfl_xor(pm, 2));
            pm = fmaxf(pm, __shfl_xor(pm, 4));
            pm = fmaxf(pm, __shfl_xor(pm, 8));
            const float mnew = fmaxf(m_r[j], pm);
            const float alpha = exp2f(m_r[j] - mnew);
            const float p0 = exp2f(s0 - mnew);
            const float p1 = exp2f(s1 - mnew);
            const float p2 = exp2f(s2 - mnew);
            const float p3 = exp2f(s3 - mnew);
            float rsum = p0 + p1 + p2 + p3;
            rsum += __shfl_xor(rsum, 1);
            rsum += __shfl_xor(rsum, 2);
            rsum += __shfl_xor(rsum, 4);
            rsum += __shfl_xor(rsum, 8);
            l_r[j] = l_r[j] * alpha + rsum;
            m_r[j] = mnew;
#pragma unroll
            for (int df = 0; df < 4; ++df) oacc[df][j] *= alpha;
            const int prow = (w * 16 + lhi * 4 + j) * 72;
            Pt[prow + llo]      = __float2bfloat16(p0);
            Pt[prow + llo + 16] = __float2bfloat16(p1);
            Pt[prow + llo + 32] = __float2bfloat16(p2);
            Pt[prow + llo + 48] = __float2bfloat16(p3);
        }

        // O += P V
#pragma unroll
        for (int ks = 0; ks < 2; ++ks) {
            const short8v pa = *(const short8v*)&Pt[(w * 16 + llo) * 72 + ks * 32 + lhi * 8];
#pragma unroll
            for (int df = 0; df < 4; ++df) {
                const short8v vb = *(const short8v*)&Vts[(df * 16 + llo) * 72 + ks * 32 + lhi * 8];
                oacc[df] = __builtin_amdgcn_mfma_f32_16x16x32_bf16(pa, vb, oacc[df], 0, 0, 0);
            }
        }
        __syncthreads();   // reads done; next iter may overwrite K/V LDS

        if (kt < 7) { kr0 = nk0; kr1 = nk1; vr0 = nv0; vr1 = nv1; }
    }

#pragma unroll
    for (int j = 0; j < 4; ++j) {
        const float inv = 1.0f / l_r[j];
        __hip_bfloat16* orow =
            o + (size_t)(b * S_ + qt * 64 + w * 16 + lhi * 4 + j) * D_ + h * 64;
#pragma unroll
        for (int df = 0; df < 4; ++df)
            orow[df * 16 + llo] = __float2bfloat16(oacc[df][j] * inv);
    }
}

// ---------------------------------------------------------------------------
// launch
// ---------------------------------------------------------------------------
extern "C" void kernel_launch(void* const* d_in, const int* in_sizes, int n_in,
                              void* d_out, int out_size, void* d_ws, size_t ws_size,
                              hipStream_t stream)
{
    const float* x    = (const float*)d_in[0];
    const int*   mask = (const int*)d_in[1];
    const float* wq   = (const float*)d_in[2];
    const float* bq   = (const float*)d_in[3];
    const float* wk   = (const float*)d_in[4];
    const float* bk   = (const float*)d_in[5];
    const float* wv   = (const float*)d_in[6];
    const float* bv   = (const float*)d_in[7];
    const float* wo   = (const float*)d_in[8];
    const float* bo   = (const float*)d_in[9];
    const float* w1   = (const float*)d_in[10];
    const float* b1   = (const float*)d_in[11];
    const float* w2   = (const float*)d_in[12];
    const float* b2   = (const float*)d_in[13];
    const float* ln1g = (const float*)d_in[14];
    const float* ln1b = (const float*)d_in[15];
    const float* ln2g = (const float*)d_in[16];
    const float* ln2b = (const float*)d_in[17];
    float* out = (float*)d_out;
    char* ws = (char*)d_ws;

    const size_t MB = 1024 * 1024;
    // ws layout (~106MB):
    //   hb bf16            : 0  - 16
    //   qbh bf16 (scaled)  : 16 - 32
    //   kbh bf16           : 32 - 48
    //   vth bf16 [B,H,DK,S]: 48 - 64
    //   attnb bf16         : 64 - 80
    //   ff1b bf16          : 16 - 80 (reuses qkv/attn after o-proj)
    //   wcat [3072][1024]  : 80 - 86 (fqq|fqk|fqv contiguous)
    //   wot 86-88, w1t 88-96, w2t 96-104
    //   scales 104MB; maskbits 105MB (512KB)
    __hip_bfloat16* hb    = (__hip_bfloat16*)(ws);
    __hip_bfloat16* qbh   = (__hip_bfloat16*)(ws + 16 * MB);
    __hip_bfloat16* kbh   = (__hip_bfloat16*)(ws + 32 * MB);
    __hip_bfloat16* vth   = (__hip_bfloat16*)(ws + 48 * MB);
    __hip_bfloat16* attnb = (__hip_bfloat16*)(ws + 64 * MB);
    __hip_bfloat16* ff1b  = (__hip_bfloat16*)(ws + 16 * MB);
    __hip_bfloat16* wcat  = (__hip_bfloat16*)(ws + 80 * MB);
    __hip_bfloat16* fqqt  = (__hip_bfloat16*)(ws + 80 * MB);
    __hip_bfloat16* fqkt  = (__hip_bfloat16*)(ws + 82 * MB);
    __hip_bfloat16* fqvt  = (__hip_bfloat16*)(ws + 84 * MB);
    __hip_bfloat16* wot   = (__hip_bfloat16*)(ws + 86 * MB);
    __hip_bfloat16* w1t   = (__hip_bfloat16*)(ws + 88 * MB);
    __hip_bfloat16* w2t   = (__hip_bfloat16*)(ws + 96 * MB);
    unsigned int*   scales = (unsigned int*)(ws + 104 * MB);
    unsigned long long* mbits = (unsigned long long*)(ws + 105 * MB);

    const int NW = D_ * D_;

    zero_scales_k<<<1, 64, 0, stream>>>(scales);
    maxabs_k<<<256, 256, 0, stream>>>(wq, scales + 0, NW);
    maxabs_k<<<256, 256, 0, stream>>>(wk, scales + 1, NW);
    maxabs_k<<<256, 256, 0, stream>>>(wv, scales + 2, NW);
    maskpack_k<<<(B_ * S_ * (S_ / 64)) / 4, 256, 0, stream>>>(mask, mbits);

    const dim3 tb(32, 8);
    transq_k<<<dim3(D_ / 32, D_ / 32), tb, 0, stream>>>(wq, scales + 0, fqqt, D_, D_);
    transq_k<<<dim3(D_ / 32, D_ / 32), tb, 0, stream>>>(wk, scales + 1, fqkt, D_, D_);
    transq_k<<<dim3(D_ / 32, D_ / 32), tb, 0, stream>>>(wv, scales + 2, fqvt, D_, D_);
    transq_k<<<dim3(D_ / 32, D_ / 32), tb, 0, stream>>>(wo, nullptr, wot, D_, D_);
    transq_k<<<dim3(DFF_ / 32, D_ / 32), tb, 0, stream>>>(w1, nullptr, w1t, D_, DFF_);
    transq_k<<<dim3(D_ / 32, DFF_ / 32), tb, 0, stream>>>(w2, nullptr, w2t, DFF_, D_);

    ln_bf16_k<<<NROW, 256, 0, stream>>>(x, ln1g, ln1b, hb);

    // fused QKV: N = 3072
    gemm_qkv<<<dim3(3 * D_ / 128, NROW / 128), 256, 0, stream>>>(
        hb, wcat, bq, bk, bv, qbh, kbh, vth);

    attn_mfma_k<<<dim3(S_ / 64, B_ * H_), 256, 0, stream>>>(qbh, kbh, vth, mbits, attnb);

    // x2 = x + attn @ wo + bo -> out (fp32)
    const dim3 gD(D_ / 128, NROW / 128);
    gemm_bf16<2, false><<<gD, 256, 0, stream>>>(attnb, wot, bo, x, out, NROW, D_, D_);

    // h2 = LN2(x2)
    ln_bf16_k<<<NROW, 256, 0, stream>>>(out, ln2g, ln2b, hb);

    // ff1 = gelu(h2 @ w1 + b1)
    gemm_bf16<1, true><<<dim3(DFF_ / 128, NROW / 128), 256, 0, stream>>>(
        hb, w1t, b1, nullptr, ff1b, NROW, DFF_, D_);

    // out = x2 + ff1 @ w2 + b2
    gemm_bf16<2, false><<<gD, 256, 0, stream>>>(ff1b, w2t, b2, out, out, NROW, D_, DFF_);
}

// Round 6
// 454.281 us; speedup vs baseline: 6.8735x; 1.1003x over previous
//
#include <hip/hip_runtime.h>
#include <hip/hip_bf16.h>
#include <math.h>

#define B_   16
#define S_   512
#define D_   1024
#define H_   16
#define DK_  64
#define DFF_ 4096
#define NROW (B_ * S_)   // 8192
#define NEG_ (-1.0e9f)
#define SCQ_ 0.18033688011112042f   // 0.125 * log2(e): QK^T lands in log2 units

typedef __attribute__((ext_vector_type(8))) short short8v;   // 8 bf16 = 4 VGPRs
typedef __attribute__((ext_vector_type(4))) float f32x4;

__device__ __forceinline__ void load_lds16(const void* g, void* l) {
    __builtin_amdgcn_global_load_lds(
        reinterpret_cast<const __attribute__((address_space(1))) unsigned int*>(
            reinterpret_cast<uintptr_t>(g)),
        reinterpret_cast<__attribute__((address_space(3))) unsigned int*>(
            reinterpret_cast<uintptr_t>(l)),
        16, 0, 0);
}

__device__ __forceinline__ ushort f2bf_raw(float f) {
    __hip_bfloat16 h = __float2bfloat16(f);
    return *(ushort*)&h;
}

__device__ __forceinline__ float gelu_f(float v) {
    return 0.5f * v * (1.0f + erff(v * 0.70710678118654752f));
}

// ---------------------------------------------------------------------------
// utility kernels
// ---------------------------------------------------------------------------
__global__ void zero_scales_k(unsigned int* p) {
    if (threadIdx.x < 3) p[threadIdx.x] = 0u;
}

__global__ void maxabs_k(const float* __restrict__ w, unsigned int* __restrict__ out, int n) {
    float m = 0.f;
    for (int i = blockIdx.x * blockDim.x + threadIdx.x; i < n; i += gridDim.x * blockDim.x)
        m = fmaxf(m, fabsf(w[i]));
#pragma unroll
    for (int off = 1; off < 64; off <<= 1)
        m = fmaxf(m, __shfl_xor(m, off));
    __shared__ float red[4];
    const int wave = threadIdx.x >> 6;
    if ((threadIdx.x & 63) == 0) red[wave] = m;
    __syncthreads();
    if (threadIdx.x == 0) {
        m = fmaxf(fmaxf(red[0], red[1]), fmaxf(red[2], red[3]));
        atomicMax(out, __float_as_uint(m));
    }
}

// pack mask (B,1,S,S) int32 -> bits[B*S*(S/64)] u64
__global__ __launch_bounds__(256) void maskpack_k(
    const int* __restrict__ mask, unsigned long long* __restrict__ bits) {
    const int g = blockIdx.x * 4 + (threadIdx.x >> 6);
    const unsigned long long bm = __ballot(mask[(size_t)g * 64 + (threadIdx.x & 63)] != 0);
    if ((threadIdx.x & 63) == 0) bits[g] = bm;
}

// transpose fp32 W[K][N] -> bf16 Wt[N][K], optional int8 fake-quant
__global__ __launch_bounds__(256) void transq_k(
    const float* __restrict__ W, const unsigned int* __restrict__ smax,
    __hip_bfloat16* __restrict__ Wt, int K, int N)
{
    __shared__ float t[32][33];
    const int n0 = blockIdx.x * 32, k0 = blockIdx.y * 32;
    const int tx = threadIdx.x, ty = threadIdx.y;
    float scale = 1.0f;
    if (smax) scale = __uint_as_float(*smax) * (1.0f / 127.0f);
#pragma unroll
    for (int i = 0; i < 4; ++i) {
        float v = W[(size_t)(k0 + ty + 8 * i) * N + n0 + tx];
        if (smax) v = rintf(v / scale) * scale;
        t[ty + 8 * i][tx] = v;
    }
    __syncthreads();
#pragma unroll
    for (int i = 0; i < 4; ++i)
        Wt[(size_t)(n0 + ty + 8 * i) * K + k0 + tx] = __float2bfloat16(t[tx][ty + 8 * i]);
}

// ---------------------------------------------------------------------------
// layer norm fp32 -> bf16
// ---------------------------------------------------------------------------
__global__ __launch_bounds__(256) void ln_bf16_k(
    const float* __restrict__ x, const float* __restrict__ g,
    const float* __restrict__ b, __hip_bfloat16* __restrict__ y)
{
    const int row = blockIdx.x;
    const int tid = threadIdx.x;
    const float4 v = *(const float4*)&x[(size_t)row * D_ + tid * 4];

    float s = v.x + v.y + v.z + v.w;
#pragma unroll
    for (int off = 1; off < 64; off <<= 1) s += __shfl_xor(s, off);
    __shared__ float red[8];
    const int wave = tid >> 6, lane = tid & 63;
    if (lane == 0) red[wave] = s;
    __syncthreads();
    s = red[0] + red[1] + red[2] + red[3];
    const float mu = s * (1.0f / (float)D_);

    const float d0 = v.x - mu, d1 = v.y - mu, d2 = v.z - mu, d3 = v.w - mu;
    float sq = d0 * d0 + d1 * d1 + d2 * d2 + d3 * d3;
#pragma unroll
    for (int off = 1; off < 64; off <<= 1) sq += __shfl_xor(sq, off);
    if (lane == 0) red[4 + wave] = sq;
    __syncthreads();
    sq = red[4] + red[5] + red[6] + red[7];
    const float rs = 1.0f / sqrtf(sq * (1.0f / (float)D_) + 1e-5f);

    const float4 gv = *(const float4*)&g[tid * 4];
    const float4 bv = *(const float4*)&b[tid * 4];
    union { ushort4 u4; ushort u[4]; } cv;
    cv.u[0] = f2bf_raw(d0 * rs * gv.x + bv.x);
    cv.u[1] = f2bf_raw(d1 * rs * gv.y + bv.y);
    cv.u[2] = f2bf_raw(d2 * rs * gv.z + bv.z);
    cv.u[3] = f2bf_raw(d3 * rs * gv.w + bv.w);
    *(ushort4*)&y[(size_t)row * D_ + tid * 4] = cv.u4;
}

// ---------------------------------------------------------------------------
// 256-wide 8-phase MFMA GEMM.  C[M,N] = A[M,K] @ Bt[N,K]^T + epilogue.
// 512 threads = 8 waves (2M x 4N). BM=256, BN=BNT*64, BK=64. dbuf LDS.
// Swizzle: source-prepermuted klog = (lane&7)^(lane>>3); reads XOR chunk
// with llo&7 (m214-verified involution; rule #21 both-sides).
// Counted vmcnt protocol (per wave, stage order B0,B1,A0,A1):
//   phase2-end: vmcnt(2*SB) retires A1(cur) before phases 3-4 read it
//   phase4-end: vmcnt(2) retires B0,B1,A0(next), leaves A1(next) in flight
// Waits precede the phase-end s_barrier -> cross-wave staging is complete
// before any wave's next-phase ds_reads.
// EPI: 1 = bias+gelu -> bf16 (FFN1)
//      2 = bias+residual -> fp32 (o-proj, FFN2)
//      3 = QKV split: proj0 -> C*SCQ_ bf16, proj1 -> C2 bf16, proj2 -> C3 vth
// ---------------------------------------------------------------------------
template <int BNT, int EPI>
__global__ __launch_bounds__(512, 2) void gemm256(
    const __hip_bfloat16* __restrict__ A, const __hip_bfloat16* __restrict__ Bt,
    const float* __restrict__ bias, const float* __restrict__ bias2,
    const float* __restrict__ bias3, const float* __restrict__ res,
    void* __restrict__ C, void* __restrict__ C2, void* __restrict__ C3,
    int M, int N, int K)
{
    constexpr int BN   = BNT * 64;
    constexpr int ABYT = 256 * 128;        // A tile bytes per buffer
    constexpr int BBYT = BN * 128;         // B tile bytes per buffer
    constexpr int BUF  = ABYT + BBYT;
    constexpr int SB   = BNT / 2;          // gload issues per B half-tile
    __shared__ __align__(16) char smem[2 * BUF];

    const int tid = threadIdx.x;
    const int w = tid >> 6, lane = tid & 63;
    const int llo = lane & 15, lhi = lane >> 4;
    const int wr = w >> 2, wc = w & 3;

    // XCD swizzle (all grids are %8 == 0)
    const int nwg = gridDim.x;
    const int bid = blockIdx.x;
    const int swz = (bid & 7) * (nwg >> 3) + (bid >> 3);
    const int nby = M >> 8;
    const int by = swz % nby, bx = swz / nby;
    const int row0 = by * 256, col0 = bx * BN;

    // per-lane swizzled chunk byte offsets for fragment reads (kk = 0,1)
    const int cko0 = ((lhi) ^ (llo & 7)) * 16;
    const int cko1 = ((4 + lhi) ^ (llo & 7)) * 16;

    // staging source decode (per-lane pre-swizzled global addresses)
    const int l3 = lane >> 3;                       // 0..7
    const int klog8 = ((lane & 7) ^ l3) * 8;        // element offset in K
    const int rA_base = ((w >> 1) & 3) * 16 + (w & 1) * 8 + l3;
    const int rB_ws = w * 8 + l3;

    const __hip_bfloat16* Asrc[2][2];
#pragma unroll
    for (int h = 0; h < 2; ++h)
#pragma unroll
        for (int s = 0; s < 2; ++s)
            Asrc[h][s] = A + (size_t)(row0 + s * 128 + h * 64 + rA_base) * K + klog8;
    const __hip_bfloat16* Bsrc[2][2];
#pragma unroll
    for (int h = 0; h < 2; ++h)
#pragma unroll
        for (int s = 0; s < 2; ++s)
            Bsrc[h][s] = Bt + (size_t)(col0 + h * (BN / 2) + (SB == 2 ? s * 64 : 0) + rB_ws) * K + klog8;

#define STAGE_A(bufv, hh, tt) do {                                                            \
    load_lds16(Asrc[hh][0] + (size_t)(tt) * 64, smem + (bufv) * BUF + (hh) * 16384 + w * 1024);        \
    load_lds16(Asrc[hh][1] + (size_t)(tt) * 64, smem + (bufv) * BUF + (hh) * 16384 + 8192 + w * 1024); \
} while (0)
#define STAGE_B(bufv, hh, tt) do {                                                                     \
    load_lds16(Bsrc[hh][0] + (size_t)(tt) * 64, smem + (bufv) * BUF + ABYT + (hh) * (BBYT / 2) + w * 1024); \
    if (SB == 2)                                                                                       \
        load_lds16(Bsrc[hh][1] + (size_t)(tt) * 64, smem + (bufv) * BUF + ABYT + (hh) * (BBYT / 2) + 8192 + w * 1024); \
} while (0)

    f32x4 acc[8][BNT] = {};
    const int NT = K >> 6;

    // prologue: stage tile 0 into buf 0 (order B0,B1,A0,A1), leave A1 in flight
    STAGE_B(0, 0, 0); STAGE_B(0, 1, 0); STAGE_A(0, 0, 0); STAGE_A(0, 1, 0);
    asm volatile("s_waitcnt vmcnt(2)");
    __builtin_amdgcn_sched_barrier(0);
    __builtin_amdgcn_s_barrier();
    __builtin_amdgcn_sched_barrier(0);

    short8v bfr[BNT][2];
    for (int t = 0; t < NT; ++t) {
        const int buf = t & 1;
        const bool more = (t + 1) < NT;
        char* const base = smem + buf * BUF;
#pragma unroll
        for (int ph = 0; ph < 4; ++ph) {
            // ---- ds_reads for this phase ----
            if (ph == 0) {
#pragma unroll
                for (int n = 0; n < BNT; ++n) {
                    const int brow = wc * (BNT * 16) + n * 16 + llo;
                    bfr[n][0] = *(const short8v*)(base + ABYT + brow * 128 + cko0);
                    bfr[n][1] = *(const short8v*)(base + ABYT + brow * 128 + cko1);
                }
            }
            const int mf0 = ph * 2, mf1 = ph * 2 + 1;
            const int slot0 = (mf0 >> 2) * 128 + wr * 64 + (mf0 & 3) * 16 + llo;
            const int slot1 = (mf1 >> 2) * 128 + wr * 64 + (mf1 & 3) * 16 + llo;
            const short8v a0k0 = *(const short8v*)(base + slot0 * 128 + cko0);
            const short8v a0k1 = *(const short8v*)(base + slot0 * 128 + cko1);
            const short8v a1k0 = *(const short8v*)(base + slot1 * 128 + cko0);
            const short8v a1k1 = *(const short8v*)(base + slot1 * 128 + cko1);
            // ---- stage one half-tile of next K-tile ----
            if (more) {
                if (ph == 0) STAGE_B(buf ^ 1, 0, t + 1);
                if (ph == 1) STAGE_B(buf ^ 1, 1, t + 1);
                if (ph == 2) STAGE_A(buf ^ 1, 0, t + 1);
                if (ph == 3) STAGE_A(buf ^ 1, 1, t + 1);
            }
            __builtin_amdgcn_s_barrier();
            __builtin_amdgcn_sched_barrier(0);
            // ---- MFMA cluster ----
            __builtin_amdgcn_s_setprio(1);
#pragma unroll
            for (int n = 0; n < BNT; ++n) {
                acc[mf0][n] = __builtin_amdgcn_mfma_f32_16x16x32_bf16(a0k0, bfr[n][0], acc[mf0][n], 0, 0, 0);
                acc[mf0][n] = __builtin_amdgcn_mfma_f32_16x16x32_bf16(a0k1, bfr[n][1], acc[mf0][n], 0, 0, 0);
                acc[mf1][n] = __builtin_amdgcn_mfma_f32_16x16x32_bf16(a1k0, bfr[n][0], acc[mf1][n], 0, 0, 0);
                acc[mf1][n] = __builtin_amdgcn_mfma_f32_16x16x32_bf16(a1k1, bfr[n][1], acc[mf1][n], 0, 0, 0);
            }
            __builtin_amdgcn_s_setprio(0);
            // ---- phase-end waits (before barrier -> cross-wave guarantee) ----
            if (ph == 1) {
                if (more) { asm volatile("s_waitcnt vmcnt(%0)" :: "i"(2 * SB)); }
                else      { asm volatile("s_waitcnt vmcnt(0)"); }
            }
            if (ph == 3) { asm volatile("s_waitcnt vmcnt(2)"); }
            __builtin_amdgcn_sched_barrier(0);
            __builtin_amdgcn_s_barrier();
            __builtin_amdgcn_sched_barrier(0);
        }
    }
#undef STAGE_A
#undef STAGE_B

    // epilogue. C/D: col = llo, row = lhi*4 + j
#pragma unroll
    for (int n = 0; n < BNT; ++n) {
        const int col = col0 + wc * (BNT * 16) + n * 16 + llo;
        if (EPI == 3) {
            const int proj = col0 >> 10;        // block-uniform (256-col blocks)
            const int lcol = col & 1023;
            const float bs = (proj == 0 ? bias : proj == 1 ? bias2 : bias3)[lcol];
#pragma unroll
            for (int mf = 0; mf < 8; ++mf) {
                const int rbase = row0 + wr * 128 + mf * 16 + lhi * 4;
                if (proj == 2) {
                    const int bb = rbase >> 9, srow = rbase & 511;
                    const int hh = lcol >> 6, dk = lcol & 63;
                    union { ushort4 u4; ushort u[4]; } pk;
#pragma unroll
                    for (int j = 0; j < 4; ++j) pk.u[j] = f2bf_raw(acc[mf][n][j] + bs);
                    *(ushort4*)&((ushort*)C3)[(((size_t)(bb * 16 + hh) * 64 + dk) << 9) + srow] = pk.u4;
                } else {
                    __hip_bfloat16* dst = proj == 0 ? (__hip_bfloat16*)C : (__hip_bfloat16*)C2;
                    const float sc = proj == 0 ? SCQ_ : 1.0f;
#pragma unroll
                    for (int j = 0; j < 4; ++j)
                        dst[(size_t)(rbase + j) * D_ + lcol] = __float2bfloat16((acc[mf][n][j] + bs) * sc);
                }
            }
        } else {
            const float bs = bias[col];
#pragma unroll
            for (int mf = 0; mf < 8; ++mf) {
                const int rbase = row0 + wr * 128 + mf * 16 + lhi * 4;
#pragma unroll
                for (int j = 0; j < 4; ++j) {
                    float v = acc[mf][n][j] + bs;
                    if (EPI == 1) v = gelu_f(v);
                    if (EPI == 2) v += res[(size_t)(rbase + j) * N + col];
                    if (EPI == 1) ((__hip_bfloat16*)C)[(size_t)(rbase + j) * N + col] = __float2bfloat16(v);
                    else          ((float*)C)[(size_t)(rbase + j) * N + col] = v;
                }
            }
        }
    }
}

// ---------------------------------------------------------------------------
// MFMA flash attention (unchanged from round 5).
// ---------------------------------------------------------------------------
__global__ __launch_bounds__(256) void attn_mfma_k(
    const __hip_bfloat16* __restrict__ q, const __hip_bfloat16* __restrict__ k,
    const __hip_bfloat16* __restrict__ vt, const unsigned long long* __restrict__ mbits,
    __hip_bfloat16* __restrict__ o)
{
    const int qt = blockIdx.x;
    const int bh = blockIdx.y;
    const int b = bh >> 4, h = bh & 15;

    __shared__ __align__(16) __hip_bfloat16 Qs[64 * 72];
    __shared__ __align__(16) __hip_bfloat16 Ks[64 * 72];
    __shared__ __align__(16) __hip_bfloat16 Vts[64 * 72];
    __shared__ __align__(16) __hip_bfloat16 Pt[64 * 72];

    const int tid = threadIdx.x;
    const int w = tid >> 6, l = tid & 63;
    const int llo = l & 15, lhi = l >> 4;
    const int srow = tid >> 2, schk = tid & 3;

    {
        const __hip_bfloat16* qg =
            q + (size_t)(b * S_ + qt * 64 + srow) * D_ + h * 64 + schk * 16;
        *(short8v*)&Qs[srow * 72 + schk * 16] = *(const short8v*)qg;
        *(short8v*)&Qs[srow * 72 + schk * 16 + 8] = *(const short8v*)(qg + 8);
    }

    const __hip_bfloat16* kptr = k + (size_t)(b * S_ + srow) * D_ + h * 64 + schk * 16;
    const __hip_bfloat16* vptr = vt + (((size_t)(b * 16 + h) * 64 + srow) << 9) + schk * 16;
    short8v kr0 = *(const short8v*)kptr;
    short8v kr1 = *(const short8v*)(kptr + 8);
    short8v vr0 = *(const short8v*)vptr;
    short8v vr1 = *(const short8v*)(vptr + 8);

    __syncthreads();

    const short8v qa0 = *(const short8v*)&Qs[(w * 16 + llo) * 72 + lhi * 8];
    const short8v qa1 = *(const short8v*)&Qs[(w * 16 + llo) * 72 + 32 + lhi * 8];

    const unsigned long long* mrow =
        mbits + (((size_t)(b * S_ + qt * 64 + w * 16 + lhi * 4)) << 3);

    f32x4 oacc[4] = {};
    float m_r[4] = {-INFINITY, -INFINITY, -INFINITY, -INFINITY};
    float l_r[4] = {0.f, 0.f, 0.f, 0.f};

    for (int kt = 0; kt < 8; ++kt) {
        *(short8v*)&Ks[srow * 72 + schk * 16] = kr0;
        *(short8v*)&Ks[srow * 72 + schk * 16 + 8] = kr1;
        *(short8v*)&Vts[srow * 72 + schk * 16] = vr0;
        *(short8v*)&Vts[srow * 72 + schk * 16 + 8] = vr1;
        __syncthreads();

        short8v nk0, nk1, nv0, nv1;
        if (kt < 7) {
            const __hip_bfloat16* kp = kptr + (size_t)(kt + 1) * (64 * D_);
            const __hip_bfloat16* vp = vptr + (kt + 1) * 64;
            nk0 = *(const short8v*)kp;
            nk1 = *(const short8v*)(kp + 8);
            nv0 = *(const short8v*)vp;
            nv1 = *(const short8v*)(vp + 8);
        }

        f32x4 sacc[4] = {};
#pragma unroll
        for (int n = 0; n < 4; ++n)
            sacc[n] = __builtin_amdgcn_mfma_f32_16x16x32_bf16(
                qa0, *(const short8v*)&Ks[(n * 16 + llo) * 72 + lhi * 8], sacc[n], 0, 0, 0);
#pragma unroll
        for (int n = 0; n < 4; ++n)
            sacc[n] = __builtin_amdgcn_mfma_f32_16x16x32_bf16(
                qa1, *(const short8v*)&Ks[(n * 16 + llo) * 72 + 32 + lhi * 8], sacc[n], 0, 0, 0);

#pragma unroll
        for (int j = 0; j < 4; ++j) {
            const unsigned long long mb = mrow[j * 8 + kt];
            const float s0 = ((mb >> llo) & 1ull)        ? sacc[0][j] : NEG_;
            const float s1 = ((mb >> (llo + 16)) & 1ull) ? sacc[1][j] : NEG_;
            const float s2 = ((mb >> (llo + 32)) & 1ull) ? sacc[2][j] : NEG_;
            const float s3 = ((mb >> (llo + 48)) & 1ull) ? sacc[3][j] : NEG_;
            float pm = fmaxf(fmaxf(s0, s1), fmaxf(s2, s3));
            pm = fmaxf(pm, __shfl_xor(pm, 1));
            pm = fmaxf(pm, __shfl_xor(pm, 2));
            pm = fmaxf(pm, __shfl_xor(pm, 4));
            pm = fmaxf(pm, __shfl_xor(pm, 8));
            const float mnew = fmaxf(m_r[j], pm);
            const float alpha = exp2f(m_r[j] - mnew);
            const float p0 = exp2f(s0 - mnew);
            const float p1 = exp2f(s1 - mnew);
            const float p2 = exp2f(s2 - mnew);
            const float p3 = exp2f(s3 - mnew);
            float rsum = p0 + p1 + p2 + p3;
            rsum += __shfl_xor(rsum, 1);
            rsum += __shfl_xor(rsum, 2);
            rsum += __shfl_xor(rsum, 4);
            rsum += __shfl_xor(rsum, 8);
            l_r[j] = l_r[j] * alpha + rsum;
            m_r[j] = mnew;
#pragma unroll
            for (int df = 0; df < 4; ++df) oacc[df][j] *= alpha;
            const int prow = (w * 16 + lhi * 4 + j) * 72;
            Pt[prow + llo]      = __float2bfloat16(p0);
            Pt[prow + llo + 16] = __float2bfloat16(p1);
            Pt[prow + llo + 32] = __float2bfloat16(p2);
            Pt[prow + llo + 48] = __float2bfloat16(p3);
        }

#pragma unroll
        for (int ks = 0; ks < 2; ++ks) {
            const short8v pa = *(const short8v*)&Pt[(w * 16 + llo) * 72 + ks * 32 + lhi * 8];
#pragma unroll
            for (int df = 0; df < 4; ++df) {
                const short8v vb = *(const short8v*)&Vts[(df * 16 + llo) * 72 + ks * 32 + lhi * 8];
                oacc[df] = __builtin_amdgcn_mfma_f32_16x16x32_bf16(pa, vb, oacc[df], 0, 0, 0);
            }
        }
        __syncthreads();

        if (kt < 7) { kr0 = nk0; kr1 = nk1; vr0 = nv0; vr1 = nv1; }
    }

#pragma unroll
    for (int j = 0; j < 4; ++j) {
        const float inv = 1.0f / l_r[j];
        __hip_bfloat16* orow =
            o + (size_t)(b * S_ + qt * 64 + w * 16 + lhi * 4 + j) * D_ + h * 64;
#pragma unroll
        for (int df = 0; df < 4; ++df)
            orow[df * 16 + llo] = __float2bfloat16(oacc[df][j] * inv);
    }
}

// ---------------------------------------------------------------------------
// launch
// ---------------------------------------------------------------------------
extern "C" void kernel_launch(void* const* d_in, const int* in_sizes, int n_in,
                              void* d_out, int out_size, void* d_ws, size_t ws_size,
                              hipStream_t stream)
{
    const float* x    = (const float*)d_in[0];
    const int*   mask = (const int*)d_in[1];
    const float* wq   = (const float*)d_in[2];
    const float* bq   = (const float*)d_in[3];
    const float* wk   = (const float*)d_in[4];
    const float* bk   = (const float*)d_in[5];
    const float* wv   = (const float*)d_in[6];
    const float* bv   = (const float*)d_in[7];
    const float* wo   = (const float*)d_in[8];
    const float* bo   = (const float*)d_in[9];
    const float* w1   = (const float*)d_in[10];
    const float* b1   = (const float*)d_in[11];
    const float* w2   = (const float*)d_in[12];
    const float* b2   = (const float*)d_in[13];
    const float* ln1g = (const float*)d_in[14];
    const float* ln1b = (const float*)d_in[15];
    const float* ln2g = (const float*)d_in[16];
    const float* ln2b = (const float*)d_in[17];
    float* out = (float*)d_out;
    char* ws = (char*)d_ws;

    const size_t MB = 1024 * 1024;
    __hip_bfloat16* hb    = (__hip_bfloat16*)(ws);
    __hip_bfloat16* qbh   = (__hip_bfloat16*)(ws + 16 * MB);
    __hip_bfloat16* kbh   = (__hip_bfloat16*)(ws + 32 * MB);
    __hip_bfloat16* vth   = (__hip_bfloat16*)(ws + 48 * MB);
    __hip_bfloat16* attnb = (__hip_bfloat16*)(ws + 64 * MB);
    __hip_bfloat16* ff1b  = (__hip_bfloat16*)(ws + 16 * MB);
    __hip_bfloat16* wcat  = (__hip_bfloat16*)(ws + 80 * MB);
    __hip_bfloat16* fqqt  = (__hip_bfloat16*)(ws + 80 * MB);
    __hip_bfloat16* fqkt  = (__hip_bfloat16*)(ws + 82 * MB);
    __hip_bfloat16* fqvt  = (__hip_bfloat16*)(ws + 84 * MB);
    __hip_bfloat16* wot   = (__hip_bfloat16*)(ws + 86 * MB);
    __hip_bfloat16* w1t   = (__hip_bfloat16*)(ws + 88 * MB);
    __hip_bfloat16* w2t   = (__hip_bfloat16*)(ws + 96 * MB);
    unsigned int*   scales = (unsigned int*)(ws + 104 * MB);
    unsigned long long* mbits = (unsigned long long*)(ws + 105 * MB);

    const int NW = D_ * D_;

    zero_scales_k<<<1, 64, 0, stream>>>(scales);
    maxabs_k<<<256, 256, 0, stream>>>(wq, scales + 0, NW);
    maxabs_k<<<256, 256, 0, stream>>>(wk, scales + 1, NW);
    maxabs_k<<<256, 256, 0, stream>>>(wv, scales + 2, NW);
    maskpack_k<<<(B_ * S_ * (S_ / 64)) / 4, 256, 0, stream>>>(mask, mbits);

    const dim3 tb(32, 8);
    transq_k<<<dim3(D_ / 32, D_ / 32), tb, 0, stream>>>(wq, scales + 0, fqqt, D_, D_);
    transq_k<<<dim3(D_ / 32, D_ / 32), tb, 0, stream>>>(wk, scales + 1, fqkt, D_, D_);
    transq_k<<<dim3(D_ / 32, D_ / 32), tb, 0, stream>>>(wv, scales + 2, fqvt, D_, D_);
    transq_k<<<dim3(D_ / 32, D_ / 32), tb, 0, stream>>>(wo, nullptr, wot, D_, D_);
    transq_k<<<dim3(DFF_ / 32, D_ / 32), tb, 0, stream>>>(w1, nullptr, w1t, D_, DFF_);
    transq_k<<<dim3(D_ / 32, DFF_ / 32), tb, 0, stream>>>(w2, nullptr, w2t, DFF_, D_);

    ln_bf16_k<<<NROW, 256, 0, stream>>>(x, ln1g, ln1b, hb);

    // fused QKV: N = 3072, BNT=4  -> grid 12*32 = 384
    gemm256<4, 3><<<(3 * D_ / 256) * (NROW / 256), 512, 0, stream>>>(
        hb, wcat, bq, bk, bv, nullptr, qbh, kbh, vth, NROW, 3 * D_, D_);

    attn_mfma_k<<<dim3(S_ / 64, B_ * H_), 256, 0, stream>>>(qbh, kbh, vth, mbits, attnb);

    // x2 = x + attn @ wo + bo -> out (fp32).  BNT=2 -> grid 8*32 = 256
    gemm256<2, 2><<<(D_ / 128) * (NROW / 256), 512, 0, stream>>>(
        attnb, wot, bo, nullptr, nullptr, x, out, nullptr, nullptr, NROW, D_, D_);

    ln_bf16_k<<<NROW, 256, 0, stream>>>(out, ln2g, ln2b, hb);

    // ff1 = gelu(h2 @ w1 + b1) -> bf16.  BNT=4 -> grid 16*32 = 512
    gemm256<4, 1><<<(DFF_ / 256) * (NROW / 256), 512, 0, stream>>>(
        hb, w1t, b1, nullptr, nullptr, nullptr, ff1b, nullptr, nullptr, NROW, DFF_, D_);

    // out = x2 + ff1 @ w2 + b2 (fp32, res==C aliasing is per-thread-safe)
    gemm256<2, 2><<<(D_ / 128) * (NROW / 256), 512, 0, stream>>>(
        ff1b, w2t, b2, nullptr, nullptr, out, out, nullptr, nullptr, NROW, D_, DFF_);
}